// Round 15
// baseline (1687.619 us; speedup 1.0000x reference)
//
#include <hip/hip_runtime.h>
#include <hip/hip_bf16.h>

#define B_   8
#define N_   1024
#define TD_  5120
#define SD_  2048
#define BD_  1024
#define K_   16
#define H_   8

typedef unsigned short u16;
typedef __attribute__((ext_vector_type(8))) short bf16x8;
typedef __attribute__((ext_vector_type(4))) float f32x4;
typedef __attribute__((ext_vector_type(8))) u16 u16x8;
typedef __attribute__((ext_vector_type(4))) u16 u16x4;

__device__ __forceinline__ float bf2f(u16 u) {
    union { unsigned int i; float f; } x; x.i = ((unsigned)u) << 16; return x.f;
}
__device__ __forceinline__ u16 f2bf(float f) {
    union { float f; unsigned int i; } x; x.f = f;
    unsigned int i = x.i;
    return (u16)((i + 0x7fffu + ((i >> 16) & 1u)) >> 16);
}
__device__ __forceinline__ float gelu_exact(float v) {
    return 0.5f * v * (1.0f + erff(v * 0.70710678118654752f));
}
__device__ __forceinline__ void gload_lds16(const void* g, void* l) {
    __builtin_amdgcn_global_load_lds(
        (const __attribute__((address_space(1))) unsigned int*)g,
        (__attribute__((address_space(3))) unsigned int*)l, 16, 0, 0);
}

struct Ptr5 { const float* p[5]; };
struct Ptr40 { const float* p[8][5]; };

// ====== 128x128 m97-style GEMM, BK=64, single-buffer, 5 blocks/CU (160KB LDS)
template<int EPI, int AMODE>
__global__ __launch_bounds__(256, 5)
void gemm128(const u16* __restrict__ Abase,
             const u16* __restrict__ Bbase, long bStride,
             const float* __restrict__ biasBase, int biasStride,
             u16* __restrict__ Cbase, int ldc, long cStride, int Kd,
             const int* __restrict__ units_a, const int* __restrict__ units_b)
{
    __shared__ char lds[32768];           // A 16 KB | B 16 KB
    const int u = blockIdx.z;
    const int ua = units_a[u];
    const int ub = (AMODE == 0) ? units_b[u] : u;
    const u16* A  = Abase + (size_t)ub * 1024 * Kd;
    const u16* Bt = Bbase + (size_t)ua * bStride;
    const float* bias = biasBase + (size_t)ua * biasStride;
    u16* C = Cbase + (size_t)u * cStride;

    const int tid  = threadIdx.x;
    const int wave = tid >> 6, lane = tid & 63;
    const int wm = wave >> 1, wn = wave & 1;
    const int row0 = blockIdx.x * 128, col0 = blockIdx.y * 128;

    const int srow = tid >> 3;                       // 0..31
    const int scol = ((tid & 7) ^ (srow & 7)) << 3;  // elems
    const char* aSrc = (const char*)(A  + (size_t)(row0 + srow) * Kd + scol);
    const char* bSrc = (const char*)(Bt + (size_t)(col0 + srow) * Kd + scol);
    const int ldsW = wave * 1024;

    const int fr = lane & 15, fq = lane >> 4;
    const int kl  = fq << 4;
    const int swz = (fr & 7) << 4;

    f32x4 acc[4][4] = {};

#define LDA_(mf, kk) (*(const bf16x8*)(lds + \
    (wm*64 + (mf)*16 + fr)*128 + ((((kk)*64) + kl) ^ swz)))
#define LDB_(nf, kk) (*(const bf16x8*)(lds + 16384 + \
    (wn*64 + (nf)*16 + fr)*128 + ((((kk)*64) + kl) ^ swz)))

    const int nt = Kd >> 6;
    for (int T = 0; T < nt; ++T) {
        const size_t kb = (size_t)T << 7;
#pragma unroll
        for (int l = 0; l < 4; ++l)
            gload_lds16(aSrc + (size_t)(l*32)*Kd*2 + kb, lds + l*4096 + ldsW);
#pragma unroll
        for (int l = 0; l < 4; ++l)
            gload_lds16(bSrc + (size_t)(l*32)*Kd*2 + kb, lds + 16384 + l*4096 + ldsW);
        asm volatile("s_waitcnt vmcnt(0)" ::: "memory");
        __syncthreads();
#pragma unroll
        for (int kk = 0; kk < 2; ++kk) {
            bf16x8 aF[4], bF[4];
#pragma unroll
            for (int i = 0; i < 4; ++i) aF[i] = LDA_(i, kk);
#pragma unroll
            for (int n = 0; n < 4; ++n) bF[n] = LDB_(n, kk);
#pragma unroll
            for (int i = 0; i < 4; ++i)
#pragma unroll
                for (int n = 0; n < 4; ++n)
                    acc[i][n] = __builtin_amdgcn_mfma_f32_16x16x32_bf16(
                        aF[i], bF[n], acc[i][n], 0, 0, 0);
        }
        __syncthreads();
    }

#undef LDA_
#undef LDB_

#pragma unroll
    for (int mf = 0; mf < 4; ++mf)
#pragma unroll
        for (int nf = 0; nf < 4; ++nf) {
            const int col = col0 + wn*64 + nf*16 + fr;
            const float bv = bias[col];
#pragma unroll
            for (int j = 0; j < 4; ++j) {
                const int row = row0 + wm*64 + mf*16 + fq*4 + j;
                float v = acc[mf][nf][j] + bv;
                if (EPI == 1) v = gelu_exact(v);
                C[(size_t)row*ldc + col] = f2bf(v);
            }
        }
}

// ============ 256x256 counted-vmcnt GEMM (r7/r12, validated) ============
template<int EPI, int AMODE>
__global__ __launch_bounds__(512, 2)
void gemm256(const u16* __restrict__ Abase,
             const u16* __restrict__ Bbase, long bStride,
             const float* __restrict__ biasBase, int biasStride,
             u16* __restrict__ Cbase, int ldc, long cStride, int Kd,
             const int* __restrict__ units_a, const int* __restrict__ units_b)
{
    __shared__ char lds[131072];
    const int u = blockIdx.z;
    const int ua = units_a[u];
    const int ub = (AMODE == 0) ? units_b[u] : u;
    const u16* A  = Abase + (size_t)ub * 1024 * Kd;
    const u16* Bt = Bbase + (size_t)ua * bStride;
    const float* bias = biasBase + (size_t)ua * biasStride;
    u16* C = Cbase + (size_t)u * cStride;

    const int tid  = threadIdx.x;
    const int wave = tid >> 6, lane = tid & 63;
    const int wm = wave >> 2, wn = wave & 3;
    const int row0 = blockIdx.x * 256, col0 = blockIdx.y * 256;

    const int srow = tid >> 3;
    const int scol = ((tid & 7) ^ ((tid >> 3) & 7)) << 3;
    const char* aSrc = (const char*)(A  + (size_t)(row0 + srow) * Kd + scol);
    const char* bSrc = (const char*)(Bt + (size_t)(col0 + srow) * Kd + scol);
    const int ldsW = wave * 1024;

    const int fr = lane & 15, fq = lane >> 4;
    const int kl  = fq << 4;
    const int swz = (fr & 7) << 4;

    f32x4 acc[8][4] = {};
    bf16x8 aF[8], bF[4];

#define STAGE_A(bufv, hh, kt) do { \
    const char* s_ = aSrc + ((size_t)((hh)*128) * Kd + (size_t)(kt) * 64) * 2; \
    char* d_ = lds + (bufv)*65536 + (hh)*16384 + ldsW; \
    gload_lds16(s_, d_); \
    gload_lds16(s_ + (size_t)64 * Kd * 2, d_ + 8192); } while(0)
#define STAGE_B(bufv, hh, kt) do { \
    const char* s_ = bSrc + ((size_t)((hh)*128) * Kd + (size_t)(kt) * 64) * 2; \
    char* d_ = lds + (bufv)*65536 + 32768 + (hh)*16384 + ldsW; \
    gload_lds16(s_, d_); \
    gload_lds16(s_ + (size_t)64 * Kd * 2, d_ + 8192); } while(0)

#define LDA_(bufv, mf, kk) (*(const bf16x8*)(lds + (bufv)*65536 + \
    ((mf)*32 + wm*16 + fr)*128 + ((((kk)*64) + kl) ^ swz)))
#define LDB_(bufv, nf, kk) (*(const bf16x8*)(lds + (bufv)*65536 + 32768 + \
    (wn*64 + (nf)*16 + fr)*128 + ((((kk)*64) + kl) ^ swz)))

#define FENCE_ asm volatile("" ::: "memory")
#define BAR_   __builtin_amdgcn_s_barrier()
#define WAITL_ asm volatile("s_waitcnt lgkmcnt(0)" ::: "memory")
#define VM_(n) asm volatile("s_waitcnt vmcnt(" #n ")" ::: "memory")

#define READ_B(bufv, kk) { _Pragma("unroll") \
    for (int n_ = 0; n_ < 4; ++n_) bF[n_] = LDB_(bufv, n_, kk); }
#define READ_A8(bufv, kk) { _Pragma("unroll") \
    for (int i_ = 0; i_ < 8; ++i_) aF[i_] = LDA_(bufv, i_, kk); }
#define MFMA32_ { __builtin_amdgcn_s_setprio(1); \
    _Pragma("unroll") for (int i_ = 0; i_ < 8; ++i_) { \
      _Pragma("unroll") for (int n_ = 0; n_ < 4; ++n_) \
        acc[i_][n_] = __builtin_amdgcn_mfma_f32_16x16x32_bf16( \
            aF[i_], bF[n_], acc[i_][n_], 0, 0, 0); } \
    __builtin_amdgcn_s_setprio(0); }

    STAGE_A(0, 0, 0); STAGE_A(0, 1, 0);
    STAGE_B(0, 0, 0); STAGE_B(0, 1, 0);

    const int nt = Kd >> 6;
    for (int T = 0; T < nt - 1; ++T) {
        const int bufv = T & 1, nb = bufv ^ 1;
        STAGE_A(nb, 0, T + 1); STAGE_A(nb, 1, T + 1);
        VM_(4); BAR_; FENCE_;
        READ_B(bufv, 0); READ_A8(bufv, 0);
        STAGE_B(nb, 0, T + 1); STAGE_B(nb, 1, T + 1);
        WAITL_; MFMA32_;
        READ_B(bufv, 1); READ_A8(bufv, 1);
        WAITL_; MFMA32_;
        BAR_;
    }
    {
        const int bufv = (nt - 1) & 1;
        VM_(0); BAR_; FENCE_;
        READ_B(bufv, 0); READ_A8(bufv, 0);
        WAITL_; MFMA32_;
        READ_B(bufv, 1); READ_A8(bufv, 1);
        WAITL_; MFMA32_;
    }

#undef STAGE_A
#undef STAGE_B
#undef LDA_
#undef LDB_
#undef FENCE_
#undef BAR_
#undef WAITL_
#undef VM_
#undef READ_B
#undef READ_A8
#undef MFMA32_

#pragma unroll
    for (int mf = 0; mf < 8; ++mf)
#pragma unroll
        for (int nf = 0; nf < 4; ++nf) {
            const int col = col0 + wn*64 + nf*16 + fr;
            const float bv = bias[col];
#pragma unroll
            for (int j = 0; j < 4; ++j) {
                const int row = row0 + mf*32 + wm*16 + fq*4 + j;
                float v = acc[mf][nf][j] + bv;
                if (EPI == 1) v = gelu_exact(v);
                C[(size_t)row*ldc + col] = f2bf(v);
            }
        }
}

// ============ fused h->bf16 conversion + pooling partials ============
__global__ __launch_bounds__(256)
void cvt_pool(const float* __restrict__ h, u16* __restrict__ hb,
              float* __restrict__ pp) {
    const int b = blockIdx.x, nc = blockIdx.y, t = threadIdx.x;
    const float* hp = h + ((size_t)b*N_ + (size_t)nc*8)*TD_;
    u16* op = hb + ((size_t)b*N_ + (size_t)nc*8)*TD_;
    f32x4 sum[5] = {};
    for (int r = 0; r < 8; ++r) {
        const float* rp = hp + (size_t)r*TD_;
        u16* orow = op + (size_t)r*TD_;
#pragma unroll
        for (int j = 0; j < 5; ++j) {
            const int c = (t + 256*j) << 2;
            f32x4 v = *(const f32x4*)(rp + c);
            sum[j] += v;
            u16x4 o = { f2bf(v[0]), f2bf(v[1]), f2bf(v[2]), f2bf(v[3]) };
            *(u16x4*)(orow + c) = o;
        }
    }
#pragma unroll
    for (int j = 0; j < 5; ++j) {
        const int c = (t + 256*j) << 2;
        *(f32x4*)(pp + ((size_t)b*128 + nc)*TD_ + c) = sum[j];
    }
}

__global__ void pool_reduce(const float* __restrict__ pp, float* __restrict__ pooled) {
    const int idx = blockIdx.x*256 + threadIdx.x;   // 40960
    const int b = idx / TD_, c = idx % TD_;
    float s = 0.f;
    for (int nc = 0; nc < 128; ++nc) s += pp[((size_t)b*128 + nc)*TD_ + c];
    pooled[idx] = s * (1.0f/N_);
}

// ============ weight transpose, batched over 5 adapters (grid.z) ============
__global__ __launch_bounds__(256)
void cvt_transpose5(Ptr5 W5, u16* __restrict__ WtBase, long wtStride,
                    int Kd, int Nd) {
    __shared__ float t[64][65];
    const float* W = W5.p[blockIdx.z];
    u16* Wt = WtBase + (size_t)blockIdx.z * wtStride;
    const int k0 = blockIdx.x * 64, n0 = blockIdx.y * 64;
    const int tid = threadIdx.x;
#pragma unroll
    for (int i = 0; i < 4; ++i) {
        int ch = tid + i*256;
        int r = ch >> 4, c4 = (ch & 15) << 2;
        f32x4 v = *(const f32x4*)(W + (size_t)(k0 + r)*Nd + n0 + c4);
        t[r][c4] = v[0]; t[r][c4+1] = v[1]; t[r][c4+2] = v[2]; t[r][c4+3] = v[3];
    }
    __syncthreads();
#pragma unroll
    for (int i = 0; i < 2; ++i) {
        int ch = tid + i*256;
        int nr = ch >> 3, c8 = (ch & 7) << 3;
        u16x8 o;
#pragma unroll
        for (int j = 0; j < 8; ++j) o[j] = f2bf(t[c8 + j][nr]);
        *(u16x8*)(Wt + (size_t)(n0 + nr)*Kd + k0 + c8) = o;
    }
}

// ============ LayerNorm in place (bf16), unit-indexed params ============
__global__ __launch_bounds__(256)
void ln_rows_u(u16* __restrict__ X, const float* __restrict__ gslab,
               const float* __restrict__ bslab, const int* __restrict__ units_a) {
    const int row = blockIdx.x, tid = threadIdx.x;
    const int ua = units_a[row >> 10];
    const float* g  = gslab + (size_t)ua*SD_;
    const float* bt = bslab + (size_t)ua*SD_;
    u16* rp = X + (size_t)row*SD_;
    const u16x8 v = ((const u16x8*)rp)[tid];
    float f[8]; float s = 0.f, s2 = 0.f;
#pragma unroll
    for (int j = 0; j < 8; ++j) { f[j] = bf2f(v[j]); s += f[j]; s2 += f[j]*f[j]; }
    __shared__ float sa[4], sb[4];
#pragma unroll
    for (int o = 32; o > 0; o >>= 1) { s += __shfl_down(s, o); s2 += __shfl_down(s2, o); }
    if ((tid & 63) == 0) { sa[tid >> 6] = s; sb[tid >> 6] = s2; }
    __syncthreads();
    s = sa[0]+sa[1]+sa[2]+sa[3]; s2 = sb[0]+sb[1]+sb[2]+sb[3];
    const float mean = s * (1.0f/SD_);
    const float inv  = rsqrtf(s2 * (1.0f/SD_) - mean*mean + 1e-5f);
    const int c0 = tid*8;
    u16x8 o;
#pragma unroll
    for (int j = 0; j < 8; ++j) o[j] = f2bf((f[j]-mean)*inv*g[c0+j] + bt[c0+j]);
    ((u16x8*)rp)[tid] = o;
}

// ============ q-projection: split-K parallel ============
__global__ __launch_bounds__(256)
void qp_part(Ptr5 q, Ptr5 wq, float* __restrict__ Sp) {
    __shared__ float qL[16][256];
    const int a = blockIdx.y, ks = blockIdx.z;
    const int c = blockIdx.x*256 + threadIdx.x;
    const int t = threadIdx.x;
    const float* Q = q.p[a];
    for (int i = t; i < 16*256; i += 256)
        qL[i >> 8][i & 255] = Q[(size_t)(i >> 8)*SD_ + ks*256 + (i & 255)];
    __syncthreads();
    const float* W = wq.p[a] + (size_t)(ks*256)*SD_ + c;
    float acc[16] = {};
    for (int i = 0; i < 256; i += 4) {
        const float w0 = W[(size_t)i*SD_];
        const float w1 = W[(size_t)(i+1)*SD_];
        const float w2 = W[(size_t)(i+2)*SD_];
        const float w3 = W[(size_t)(i+3)*SD_];
#pragma unroll
        for (int k = 0; k < 16; ++k) {
            f32x4 q4 = *(const f32x4*)&qL[k][i];
            acc[k] += q4[0]*w0 + q4[1]*w1 + q4[2]*w2 + q4[3]*w3;
        }
    }
#pragma unroll
    for (int k = 0; k < 16; ++k)
        Sp[((size_t)(a*8 + ks)*16 + k)*SD_ + c] = acc[k];
}

__global__ void qp_reduce(const float* __restrict__ Sp, Ptr5 bq, float* __restrict__ qp) {
    const int idx = blockIdx.x*256 + threadIdx.x;   // 163840
    const int a = idx >> 15, k = (idx >> 11) & 15, c = idx & 2047;
    float s = bq.p[a][c];
#pragma unroll
    for (int ks = 0; ks < 8; ++ks)
        s += Sp[((size_t)(a*8 + ks)*16 + k)*SD_ + c];
    qp[idx] = s;
}

// ============ fused scores + softmax -> P (f32) ============
__global__ __launch_bounds__(256)
void scores_sm(const u16* __restrict__ Kb, const float* __restrict__ qp,
               const int* __restrict__ units_a, float* __restrict__ P)
{
    __shared__ float sL[16][1024];
    __shared__ float qL[16][256];
    __shared__ float red[8];
    const int u = blockIdx.x >> 3, hh = blockIdx.x & 7;
    const int ua = units_a[u];
    const int t = threadIdx.x;
    for (int i = t; i < 16*256; i += 256)
        qL[i >> 8][i & 255] = qp[(size_t)(ua*16 + (i >> 8))*SD_ + hh*256 + (i & 255)];
    __syncthreads();
    const u16* Ku = Kb + (size_t)u*1024*SD_ + hh*256;
#pragma unroll
    for (int j = 0; j < 4; ++j) {
        const int n = t + j*256;
        const u16* kr = Ku + (size_t)n*SD_;
        float acc[16] = {};
        for (int d0 = 0; d0 < 256; d0 += 8) {
            u16x8 kv8 = *(const u16x8*)(kr + d0);
            float kf[8];
#pragma unroll
            for (int e = 0; e < 8; ++e) kf[e] = bf2f(kv8[e]);
#pragma unroll
            for (int k = 0; k < 16; ++k) {
                f32x4 q0 = *(const f32x4*)&qL[k][d0];
                f32x4 q1 = *(const f32x4*)&qL[k][d0+4];
                acc[k] += q0[0]*kf[0] + q0[1]*kf[1] + q0[2]*kf[2] + q0[3]*kf[3]
                        + q1[0]*kf[4] + q1[1]*kf[5] + q1[2]*kf[6] + q1[3]*kf[7];
            }
        }
#pragma unroll
        for (int k = 0; k < 16; ++k) sL[k][n] = acc[k] * 0.0625f;
    }
    __syncthreads();
    const int lane = t & 63, wv = t >> 6;
    for (int k = 0; k < 16; ++k) {
        float v0 = sL[k][t], v1 = sL[k][t+256], v2 = sL[k][t+512], v3 = sL[k][t+768];
        float mx = fmaxf(fmaxf(v0,v1), fmaxf(v2,v3));
#pragma unroll
        for (int o = 1; o < 64; o <<= 1) mx = fmaxf(mx, __shfl_xor(mx, o));
        if (lane == 0) red[wv] = mx;
        __syncthreads();
        mx = fmaxf(fmaxf(red[0],red[1]), fmaxf(red[2],red[3]));
        float e0 = expf(v0-mx), e1 = expf(v1-mx), e2 = expf(v2-mx), e3 = expf(v3-mx);
        float s = e0+e1+e2+e3;
#pragma unroll
        for (int o = 1; o < 64; o <<= 1) s += __shfl_xor(s, o);
        if (lane == 0) red[4+wv] = s;
        __syncthreads();
        s = red[4]+red[5]+red[6]+red[7];
        const float inv = 1.0f/s;
        float* Pr = P + ((size_t)(u*8+hh)*16 + k)*1024;
        Pr[t]=e0*inv; Pr[t+256]=e1*inv; Pr[t+512]=e2*inv; Pr[t+768]=e3*inv;
        __syncthreads();
    }
}

// ============ ctx: P @ V -> ctxb (bf16) ============
__global__ __launch_bounds__(256)
void ctx_u(const u16* __restrict__ Vb, const float* __restrict__ P,
           u16* __restrict__ ctxb)
{
    __shared__ float pL[16][1024];
    const int u = blockIdx.x >> 3, hh = blockIdx.x & 7;
    const int t = threadIdx.x;
    const float* Pu = P + (size_t)(u*8+hh)*16*1024;
    for (int i = t; i < 16*1024/4; i += 256)
        ((f32x4*)&pL[0][0])[i] = ((const f32x4*)Pu)[i];
    __syncthreads();
    const u16* Vu = Vb + (size_t)u*1024*SD_ + hh*256 + t;
    float acc[16] = {};
    for (int n = 0; n < 1024; n += 4) {
        float vv0 = bf2f(Vu[(size_t)n*SD_]);
        float vv1 = bf2f(Vu[(size_t)(n+1)*SD_]);
        float vv2 = bf2f(Vu[(size_t)(n+2)*SD_]);
        float vv3 = bf2f(Vu[(size_t)(n+3)*SD_]);
#pragma unroll
        for (int k = 0; k < 16; ++k) {
            f32x4 p4 = *(const f32x4*)&pL[k][n];
            acc[k] += p4[0]*vv0 + p4[1]*vv1 + p4[2]*vv2 + p4[3]*vv3;
        }
    }
#pragma unroll
    for (int k = 0; k < 16; ++k)
        ctxb[(size_t)u*16*SD_ + k*SD_ + hh*256 + t] = f2bf(acc[k]);
}

// ============ ow-GEMM: split-K x4 ============
__global__ __launch_bounds__(256)
void gemm_ow_part(const u16* __restrict__ ctxb, const u16* __restrict__ Bslab,
                  const int* __restrict__ units_a, float* __restrict__ ctx2p)
{
    const int u = blockIdx.y, ua = units_a[u], ks = blockIdx.z;
    const int wave = threadIdx.x >> 6, lane = threadIdx.x & 63;
    const int col0 = blockIdx.x*256 + wave*64;
    const u16* A  = ctxb + (size_t)u*16*SD_;
    const u16* Bt = Bslab + (size_t)ua*SD_*SD_;
    const int fr = lane & 15, fk8 = (lane >> 4) << 3;
    f32x4 acc[4] = {};
    const int kbase = ks*512;
    for (int k0 = kbase; k0 < kbase + 512; k0 += 32) {
        bf16x8 af = *(const bf16x8*)(A + (size_t)fr*SD_ + k0 + fk8);
#pragma unroll
        for (int n = 0; n < 4; ++n) {
            bf16x8 bf8 = *(const bf16x8*)(Bt + (size_t)(col0 + n*16 + fr)*SD_ + k0 + fk8);
            acc[n] = __builtin_amdgcn_mfma_f32_16x16x32_bf16(af, bf8, acc[n], 0, 0, 0);
        }
    }
    const int fq = lane >> 4;
#pragma unroll
    for (int n = 0; n < 4; ++n)
#pragma unroll
        for (int j = 0; j < 4; ++j) {
            const int row = fq*4 + j, col = col0 + n*16 + fr;
            ctx2p[(((size_t)ks*24 + u)*16 + row)*SD_ + col] = acc[n][j];
        }
}

__global__ void gemm_ow_reduce(const float* __restrict__ ctx2p,
                               const float* __restrict__ biasSlab,
                               const int* __restrict__ units_a,
                               float* __restrict__ ctx2) {
    const int idx = blockIdx.x*256 + threadIdx.x;   // 786432
    const int u = idx / (16*SD_);
    const int rem = idx % (16*SD_);
    const int col = rem % SD_;
    float s = biasSlab[units_a[u]*SD_ + col];
#pragma unroll
    for (int ks = 0; ks < 4; ++ks)
        s += ctx2p[((size_t)ks*24*16*SD_) + (size_t)u*16*SD_ + rem];
    ctx2[idx] = s;
}

// ============ final LN ============
__global__ __launch_bounds__(256)
void ln_post_u(const float* __restrict__ ctx2, const float* __restrict__ qslab,
               const float* __restrict__ pgs, const float* __restrict__ pbs,
               const int* __restrict__ units_a, const int* __restrict__ units_b,
               float* __restrict__ out, float* __restrict__ cspec)
{
    const int k = blockIdx.x, u = blockIdx.y, tid = threadIdx.x;
    const int ua = units_a[u];
    const float* ip = ctx2 + ((size_t)u*16 + k)*SD_;
    const float* qr = qslab + ((size_t)ua*16 + k)*SD_;
    const float* g  = pgs + (size_t)ua*SD_;
    const float* bt = pbs + (size_t)ua*SD_;
    float f[8]; float s = 0.f, s2 = 0.f;
#pragma unroll
    for (int j = 0; j < 8; ++j) {
        const int c = tid + j*256;
        f[j] = ip[c] + qr[c];
        s += f[j]; s2 += f[j]*f[j];
    }
    __shared__ float sa[4], sb[4];
#pragma unroll
    for (int o = 32; o > 0; o >>= 1) { s += __shfl_down(s, o); s2 += __shfl_down(s2, o); }
    if ((tid & 63) == 0) { sa[tid >> 6] = s; sb[tid >> 6] = s2; }
    __syncthreads();
    s = sa[0]+sa[1]+sa[2]+sa[3]; s2 = sb[0]+sb[1]+sb[2]+sb[3];
    const float mean = s * (1.0f/SD_);
    const float inv  = rsqrtf(s2 * (1.0f/SD_) - mean*mean + 1e-5f);
    float* op = (u < 8) ? out + ((size_t)units_b[u]*32 + k)*SD_
                        : cspec + ((size_t)(u-8)*16 + k)*SD_;
#pragma unroll
    for (int j = 0; j < 8; ++j) { const int c = tid + j*256; op[c] = (f[j]-mean)*inv*g[c] + bt[c]; }
}

// ============ router tail ============
__global__ __launch_bounds__(256)
void rmlp_part(const float* __restrict__ pooled, const float* __restrict__ w1,
               float* __restrict__ rp) {
    const int c = blockIdx.x*256 + threadIdx.x;
    const int b = blockIdx.y, is = blockIdx.z;
    const float* pr = pooled + b*TD_ + is*512;
    const float* W = w1 + (size_t)(is*512)*512 + c;
    float s = 0.f;
    for (int i = 0; i < 512; ++i) s += pr[i] * W[(size_t)i*512];
    rp[(b*10 + is)*512 + c] = s;
}
__global__ void rmlp_reduce(const float* __restrict__ rp, const float* __restrict__ b1,
                            float* __restrict__ hid) {
    const int idx = blockIdx.x*256 + threadIdx.x;
    const int b = idx >> 9, c = idx & 511;
    float s = b1[c];
#pragma unroll
    for (int is = 0; is < 10; ++is) s += rp[(b*10 + is)*512 + c];
    hid[idx] = gelu_exact(s);
}

__global__ void router_final(const float* __restrict__ hid, const float* __restrict__ w2,
                             const float* __restrict__ b2, float* __restrict__ probs,
                             int* __restrict__ widx, float* __restrict__ wval,
                             int* __restrict__ units_a, int* __restrict__ units_b) {
    __shared__ float lg[8][4];
    __shared__ int sw[16];
    const int tid = threadIdx.x;
    if (tid < 32) {
        const int b = tid >> 2, m = tid & 3;
        float s = b2[m];
        const float* hr = hid + b*512;
        for (int i = 0; i < 512; ++i) s += hr[i]*w2[i*4 + m];
        lg[b][m] = s;
    }
    __syncthreads();
    if (tid < 8) {
        const int b = tid;
        const float l0=lg[b][0], l1=lg[b][1], l2=lg[b][2], l3=lg[b][3];
        const float mx = fmaxf(fmaxf(l0,l1),fmaxf(l2,l3));
        const float e0=expf(l0-mx), e1=expf(l1-mx), e2=expf(l2-mx), e3=expf(l3-mx);
        const float s = e0+e1+e2+e3;
        float p[4] = {e0/s, e1/s, e2/s, e3/s};
        probs[b*4+0]=p[0]; probs[b*4+1]=p[1]; probs[b*4+2]=p[2]; probs[b*4+3]=p[3];
        int i0 = 0;
        for (int m = 1; m < 4; ++m) if (p[m] > p[i0]) i0 = m;
        int i1 = -1;
        for (int m = 0; m < 4; ++m) if (m != i0 && (i1 < 0 || p[m] > p[i1])) i1 = m;
        const float w0 = p[i0], w1 = p[i1], ws = w0 + w1 + 1e-8f;
        widx[b*2]=i0; widx[b*2+1]=i1;
        wval[b*2]=w0/ws; wval[b*2+1]=w1/ws;
        sw[b*2]=i0; sw[b*2+1]=i1;
    }
    __syncthreads();
    if (tid < 24) {
        units_a[tid] = (tid < 8) ? 0 : sw[tid-8] + 1;
        units_b[tid] = (tid < 8) ? tid : ((tid-8) >> 1);
    }
}

__global__ void combine_k(const float* __restrict__ cspec, const int* __restrict__ widx,
                          const float* __restrict__ wval, float* __restrict__ out) {
    const int i = blockIdx.x*256 + threadIdx.x;
    const int c4 = i & 511;
    const int k  = (i >> 9) & 15;
    const int b  = i >> 13;
    const float w0 = wval[b*2], w1 = wval[b*2+1];
    const f32x4 v0 = ((const f32x4*)cspec)[(size_t)((2*b)  *16 + k)*512 + c4];
    const f32x4 v1 = ((const f32x4*)cspec)[(size_t)((2*b+1)*16 + k)*512 + c4];
    ((f32x4*)out)[(size_t)(b*32 + 16 + k)*512 + c4] = v0*w0 + v1*w1;
}

// ============ fused pack: bias_dw (5120) | qslab (163840) | slab8 (81920) ====
__global__ void pack_all(Ptr5 db5, Ptr5 q5, Ptr40 s8, float* __restrict__ bias_dw,
                         float* __restrict__ qslab, float* __restrict__ slab8) {
    int i = blockIdx.x*256 + threadIdx.x;   // 250880 total
    if (i < 5120) {
        bias_dw[i] = db5.p[i >> 10][i & 1023];
    } else if (i < 5120 + 163840) {
        int j = i - 5120;
        qslab[j] = q5.p[j / 32768][j % 32768];
    } else if (i < 5120 + 163840 + 81920) {
        int j = i - 5120 - 163840;
        int slab = j / 10240, rem = j % 10240;
        slab8[j] = s8.p[slab][rem / 2048][rem % 2048];
    }
}

// ============ host ============
extern "C" void kernel_launch(void* const* d_in, const int* in_sizes, int n_in,
                              void* d_out, int out_size, void* d_ws, size_t ws_size,
                              hipStream_t stream) {
    if (ws_size < 300300000ULL) return;

    const float* h = (const float*)d_in[0];
    const float* G[17]; const float* Sx[17];
    for (int i = 0; i < 17; ++i) { G[i] = (const float*)d_in[1+i]; Sx[i] = (const float*)d_in[18+i]; }
    const float* r_w1 = (const float*)d_in[35];
    const float* r_b1 = (const float*)d_in[36];
    const float* r_w2 = (const float*)d_in[37];
    const float* r_b2 = (const float*)d_in[38];

    static const size_t str[17] = {
        (size_t)TD_*BD_, BD_, (size_t)BD_*SD_, SD_, SD_, SD_, (size_t)K_*SD_,
        (size_t)SD_*SD_, (size_t)SD_*SD_, (size_t)SD_*SD_, (size_t)SD_*SD_,
        SD_, SD_, SD_, SD_, SD_, SD_ };
    auto P = [&](int pi, int a) -> const float* {
        return (a == 0) ? G[pi] : Sx[pi] + (size_t)(a-1)*str[pi];
    };

    char* w = (char*)d_ws;
    const size_t R0 = 0, R1 = 100663296, R2 = 201326592, R3 = 251658240, TAIL = 293601280;
    u16*   h_bf  = (u16*)(w + R0);
    u16*   X     = (u16*)(w + R0);
    u16*   wt_dw = (u16*)(w + R1);
    u16*   Kbuf  = (u16*)(w + R1);
    u16*   X1    = (u16*)(w + R2);
    u16*   wt_v  = (u16*)(w + R2);
    u16*   wt_ow = (u16*)(w + R2);
    u16*   wt_uw = (u16*)(w + R3);
    u16*   wt_k  = (u16*)(w + R3);
    u16*   ctxb  = (u16*)(w + R3);
    float* ctx2  = (float*)(w + R3 + 1572864);
    float* cspec = (float*)(w + R3 + 4718592);
    float* Pbuf  = (float*)(w + R3 + 6815744);
    float* ctx2p = (float*)(w + R3 + 19398656);
    float* qpp   = (float*)(w + R2);
    float* poolp = (float*)(w + R2 + 12582912);
    float* routp = (float*)(w + R2 + 33554432);
    float* qp_all  = (float*)(w + TAIL);
    float* qslab   = (float*)(w + TAIL + 655360);
    float* bias_dw = (float*)(w + TAIL + 1310720);
    float* slab8   = (float*)(w + TAIL + 1331200);
    float* pooled  = (float*)(w + TAIL + 1658880);
    float* hid     = (float*)(w + TAIL + 1822720);
    int*   widx    = (int*)  (w + TAIL + 1839104);
    float* wval    = (float*)(w + TAIL + 1839168);
    int*   units_a = (int*)  (w + TAIL + 1839232);
    int*   units_b = (int*)  (w + TAIL + 1839328);

    float* bias_uw = slab8;
    float* bias_k  = slab8 + 1*5*SD_;
    float* bias_v  = slab8 + 2*5*SD_;
    float* bias_ow = slab8 + 3*5*SD_;
    float* lng     = slab8 + 4*5*SD_;
    float* lnb     = slab8 + 5*5*SD_;
    float* pgs     = slab8 + 6*5*SD_;
    float* pbs     = slab8 + 7*5*SD_;

    float* out = (float*)d_out;

    // ---- fused conversion + pooling, then router ----
    cvt_pool<<<dim3(8, 128), 256, 0, stream>>>(h, h_bf, poolp);
    pool_reduce<<<160, 256, 0, stream>>>(poolp, pooled);
    rmlp_part<<<dim3(2, 8, 10), 256, 0, stream>>>(pooled, r_w1, routp);
    rmlp_reduce<<<16, 256, 0, stream>>>(routp, r_b1, hid);
    router_final<<<1, 64, 0, stream>>>(hid, r_w2, r_b2, out + 524288, widx, wval, units_a, units_b);

    // ---- q projections (split-K) + fused packs ----
    Ptr5 q5, wq5, bq5, db5;
    for (int a = 0; a < 5; ++a) { q5.p[a]=P(6,a); wq5.p[a]=P(7,a); bq5.p[a]=P(11,a); db5.p[a]=P(1,a); }
    qp_part<<<dim3(8, 5, 8), 256, 0, stream>>>(q5, wq5, qpp);
    qp_reduce<<<640, 256, 0, stream>>>(qpp, bq5, qp_all);
    Ptr40 s8;
    static const int slab_pi[8] = {3, 12, 13, 14, 4, 5, 15, 16};
    for (int si = 0; si < 8; ++si)
        for (int a = 0; a < 5; ++a) s8.p[si][a] = P(slab_pi[si], a);
    pack_all<<<981, 256, 0, stream>>>(db5, q5, s8, bias_dw, qslab, slab8);

    // ---- upfront transposes (batched over adapters) ----
    Ptr5 dw5, uw5, k5, v5, ow5;
    for (int a = 0; a < 5; ++a) {
        dw5.p[a] = P(0,a); uw5.p[a] = P(2,a);
        k5.p[a] = P(8,a); v5.p[a] = P(9,a); ow5.p[a] = P(10,a);
    }
    cvt_transpose5<<<dim3(TD_/64, BD_/64, 5), 256, 0, stream>>>(dw5, wt_dw, (long)BD_*TD_, TD_, BD_);
    cvt_transpose5<<<dim3(BD_/64, SD_/64, 5), 256, 0, stream>>>(uw5, wt_uw, (long)SD_*BD_, BD_, SD_);

    // ---- down-proj (gelu): gemm128 @5 blocks/CU ----
    gemm128<1, 0><<<dim3(8, 8, 24), 256, 0, stream>>>(
        h_bf, wt_dw, (long)BD_*TD_, bias_dw, BD_, X1, BD_, (long)1024*BD_, TD_, units_a, units_b);

    // ---- up-proj: gemm256 (r12 config) ----
    gemm256<0, 1><<<dim3(4, 8, 24), 512, 0, stream>>>(
        X1, wt_uw, (long)SD_*BD_, bias_uw, SD_, X, SD_, (long)1024*SD_, BD_, units_a, units_b);

    // ---- LN in place ----
    ln_rows_u<<<24*1024, 256, 0, stream>>>(X, lng, lnb, units_a);

    // ---- transposes for K/V (batched) ----
    cvt_transpose5<<<dim3(SD_/64, SD_/64, 5), 256, 0, stream>>>(k5, wt_k, (long)SD_*SD_, SD_, SD_);
    cvt_transpose5<<<dim3(SD_/64, SD_/64, 5), 256, 0, stream>>>(v5, wt_v, (long)SD_*SD_, SD_, SD_);

    // ---- K projection: gemm256 ----
    gemm256<0, 1><<<dim3(4, 8, 24), 512, 0, stream>>>(
        X, wt_k, (long)SD_*SD_, bias_k, SD_, Kbuf, SD_, (long)1024*SD_, SD_, units_a, units_b);

    // ---- scores + softmax ----
    scores_sm<<<24*8, 256, 0, stream>>>(Kbuf, qp_all, units_a, Pbuf);

    // ---- V projection ----
    gemm256<0, 1><<<dim3(4, 8, 24), 512, 0, stream>>>(
        X, wt_v, (long)SD_*SD_, bias_v, SD_, Kbuf, SD_, (long)1024*SD_, SD_, units_a, units_b);

    // ---- ow transpose (batched) ----
    cvt_transpose5<<<dim3(SD_/64, SD_/64, 5), 256, 0, stream>>>(ow5, wt_ow, (long)SD_*SD_, SD_, SD_);

    // ---- ctx = P @ V ----
    ctx_u<<<24*8, 256, 0, stream>>>(Kbuf, Pbuf, ctxb);

    // ---- output projection: split-K x4 + reduce ----
    gemm_ow_part<<<dim3(8, 24, 4), 256, 0, stream>>>(ctxb, wt_ow, units_a, ctx2p);
    gemm_ow_reduce<<<3072, 256, 0, stream>>>(ctx2p, bias_ow, units_a, ctx2);

    // ---- final LN + combine ----
    ln_post_u<<<dim3(16, 24), 256, 0, stream>>>(ctx2, qslab, pgs, pbs, units_a, units_b, out, cspec);
    combine_k<<<256, 256, 0, stream>>>(cspec, widx, wval, out);
}

// Round 16
// 1314.323 us; speedup vs baseline: 1.2840x; 1.2840x over previous
//
#include <hip/hip_runtime.h>
#include <hip/hip_bf16.h>

#define B_   8
#define N_   1024
#define TD_  5120
#define SD_  2048
#define BD_  1024
#define K_   16
#define H_   8

typedef unsigned short u16;
typedef __attribute__((ext_vector_type(8))) short bf16x8;
typedef __attribute__((ext_vector_type(4))) float f32x4;
typedef __attribute__((ext_vector_type(8))) u16 u16x8;
typedef __attribute__((ext_vector_type(4))) u16 u16x4;

__device__ __forceinline__ float bf2f(u16 u) {
    union { unsigned int i; float f; } x; x.i = ((unsigned)u) << 16; return x.f;
}
__device__ __forceinline__ u16 f2bf(float f) {
    union { float f; unsigned int i; } x; x.f = f;
    unsigned int i = x.i;
    return (u16)((i + 0x7fffu + ((i >> 16) & 1u)) >> 16);
}
__device__ __forceinline__ float gelu_exact(float v) {
    return 0.5f * v * (1.0f + erff(v * 0.70710678118654752f));
}
__device__ __forceinline__ void gload_lds16(const void* g, void* l) {
    __builtin_amdgcn_global_load_lds(
        (const __attribute__((address_space(1))) unsigned int*)g,
        (__attribute__((address_space(3))) unsigned int*)l, 16, 0, 0);
}

struct Ptr5 { const float* p[5]; };
struct Ptr40 { const float* p[8][5]; };

// ============ 128x128 m97-style GEMM, BK=64, single-buffer, 4 blocks/CU ====
template<int EPI, int AMODE>
__global__ __launch_bounds__(256, 4)
void gemm128(const u16* __restrict__ Abase,
             const u16* __restrict__ Bbase, long bStride,
             const float* __restrict__ biasBase, int biasStride,
             u16* __restrict__ Cbase, int ldc, long cStride, int Kd,
             const int* __restrict__ units_a, const int* __restrict__ units_b)
{
    __shared__ char lds[32768];           // A 16 KB | B 16 KB
    const int u = blockIdx.z;
    const int ua = units_a[u];
    const int ub = (AMODE == 0) ? units_b[u] : u;
    const u16* A  = Abase + (size_t)ub * 1024 * Kd;
    const u16* Bt = Bbase + (size_t)ua * bStride;
    const float* bias = biasBase + (size_t)ua * biasStride;
    u16* C = Cbase + (size_t)u * cStride;

    const int tid  = threadIdx.x;
    const int wave = tid >> 6, lane = tid & 63;
    const int wm = wave >> 1, wn = wave & 1;
    const int row0 = blockIdx.x * 128, col0 = blockIdx.y * 128;

    const int srow = tid >> 3;                       // 0..31
    const int scol = ((tid & 7) ^ (srow & 7)) << 3;  // elems
    const char* aSrc = (const char*)(A  + (size_t)(row0 + srow) * Kd + scol);
    const char* bSrc = (const char*)(Bt + (size_t)(col0 + srow) * Kd + scol);
    const int ldsW = wave * 1024;

    const int fr = lane & 15, fq = lane >> 4;
    const int kl  = fq << 4;
    const int swz = (fr & 7) << 4;

    f32x4 acc[4][4] = {};

#define LDA_(mf, kk) (*(const bf16x8*)(lds + \
    (wm*64 + (mf)*16 + fr)*128 + ((((kk)*64) + kl) ^ swz)))
#define LDB_(nf, kk) (*(const bf16x8*)(lds + 16384 + \
    (wn*64 + (nf)*16 + fr)*128 + ((((kk)*64) + kl) ^ swz)))

    const int nt = Kd >> 6;
    for (int T = 0; T < nt; ++T) {
        const size_t kb = (size_t)T << 7;
#pragma unroll
        for (int l = 0; l < 4; ++l)
            gload_lds16(aSrc + (size_t)(l*32)*Kd*2 + kb, lds + l*4096 + ldsW);
#pragma unroll
        for (int l = 0; l < 4; ++l)
            gload_lds16(bSrc + (size_t)(l*32)*Kd*2 + kb, lds + 16384 + l*4096 + ldsW);
        asm volatile("s_waitcnt vmcnt(0)" ::: "memory");
        __syncthreads();
#pragma unroll
        for (int kk = 0; kk < 2; ++kk) {
            bf16x8 aF[4], bF[4];
#pragma unroll
            for (int i = 0; i < 4; ++i) aF[i] = LDA_(i, kk);
#pragma unroll
            for (int n = 0; n < 4; ++n) bF[n] = LDB_(n, kk);
#pragma unroll
            for (int i = 0; i < 4; ++i)
#pragma unroll
                for (int n = 0; n < 4; ++n)
                    acc[i][n] = __builtin_amdgcn_mfma_f32_16x16x32_bf16(
                        aF[i], bF[n], acc[i][n], 0, 0, 0);
        }
        __syncthreads();
    }

#undef LDA_
#undef LDB_

#pragma unroll
    for (int mf = 0; mf < 4; ++mf)
#pragma unroll
        for (int nf = 0; nf < 4; ++nf) {
            const int col = col0 + wn*64 + nf*16 + fr;
            const float bv = bias[col];
#pragma unroll
            for (int j = 0; j < 4; ++j) {
                const int row = row0 + wm*64 + mf*16 + fq*4 + j;
                float v = acc[mf][nf][j] + bv;
                if (EPI == 1) v = gelu_exact(v);
                C[(size_t)row*ldc + col] = f2bf(v);
            }
        }
}

// ============ 256x256 counted-vmcnt GEMM (r7/r12, validated) ============
template<int EPI, int AMODE>
__global__ __launch_bounds__(512, 2)
void gemm256(const u16* __restrict__ Abase,
             const u16* __restrict__ Bbase, long bStride,
             const float* __restrict__ biasBase, int biasStride,
             u16* __restrict__ Cbase, int ldc, long cStride, int Kd,
             const int* __restrict__ units_a, const int* __restrict__ units_b)
{
    __shared__ char lds[131072];
    const int u = blockIdx.z;
    const int ua = units_a[u];
    const int ub = (AMODE == 0) ? units_b[u] : u;
    const u16* A  = Abase + (size_t)ub * 1024 * Kd;
    const u16* Bt = Bbase + (size_t)ua * bStride;
    const float* bias = biasBase + (size_t)ua * biasStride;
    u16* C = Cbase + (size_t)u * cStride;

    const int tid  = threadIdx.x;
    const int wave = tid >> 6, lane = tid & 63;
    const int wm = wave >> 2, wn = wave & 3;
    const int row0 = blockIdx.x * 256, col0 = blockIdx.y * 256;

    const int srow = tid >> 3;
    const int scol = ((tid & 7) ^ ((tid >> 3) & 7)) << 3;
    const char* aSrc = (const char*)(A  + (size_t)(row0 + srow) * Kd + scol);
    const char* bSrc = (const char*)(Bt + (size_t)(col0 + srow) * Kd + scol);
    const int ldsW = wave * 1024;

    const int fr = lane & 15, fq = lane >> 4;
    const int kl  = fq << 4;
    const int swz = (fr & 7) << 4;

    f32x4 acc[8][4] = {};
    bf16x8 aF[8], bF[4];

#define STAGE_A(bufv, hh, kt) do { \
    const char* s_ = aSrc + ((size_t)((hh)*128) * Kd + (size_t)(kt) * 64) * 2; \
    char* d_ = lds + (bufv)*65536 + (hh)*16384 + ldsW; \
    gload_lds16(s_, d_); \
    gload_lds16(s_ + (size_t)64 * Kd * 2, d_ + 8192); } while(0)
#define STAGE_B(bufv, hh, kt) do { \
    const char* s_ = bSrc + ((size_t)((hh)*128) * Kd + (size_t)(kt) * 64) * 2; \
    char* d_ = lds + (bufv)*65536 + 32768 + (hh)*16384 + ldsW; \
    gload_lds16(s_, d_); \
    gload_lds16(s_ + (size_t)64 * Kd * 2, d_ + 8192); } while(0)

#define LDA_(bufv, mf, kk) (*(const bf16x8*)(lds + (bufv)*65536 + \
    ((mf)*32 + wm*16 + fr)*128 + ((((kk)*64) + kl) ^ swz)))
#define LDB_(bufv, nf, kk) (*(const bf16x8*)(lds + (bufv)*65536 + 32768 + \
    (wn*64 + (nf)*16 + fr)*128 + ((((kk)*64) + kl) ^ swz)))

#define FENCE_ asm volatile("" ::: "memory")
#define BAR_   __builtin_amdgcn_s_barrier()
#define WAITL_ asm volatile("s_waitcnt lgkmcnt(0)" ::: "memory")
#define VM_(n) asm volatile("s_waitcnt vmcnt(" #n ")" ::: "memory")

#define READ_B(bufv, kk) { _Pragma("unroll") \
    for (int n_ = 0; n_ < 4; ++n_) bF[n_] = LDB_(bufv, n_, kk); }
#define READ_A8(bufv, kk) { _Pragma("unroll") \
    for (int i_ = 0; i_ < 8; ++i_) aF[i_] = LDA_(bufv, i_, kk); }
#define MFMA32_ { __builtin_amdgcn_s_setprio(1); \
    _Pragma("unroll") for (int i_ = 0; i_ < 8; ++i_) { \
      _Pragma("unroll") for (int n_ = 0; n_ < 4; ++n_) \
        acc[i_][n_] = __builtin_amdgcn_mfma_f32_16x16x32_bf16( \
            aF[i_], bF[n_], acc[i_][n_], 0, 0, 0); } \
    __builtin_amdgcn_s_setprio(0); }

    STAGE_A(0, 0, 0); STAGE_A(0, 1, 0);
    STAGE_B(0, 0, 0); STAGE_B(0, 1, 0);

    const int nt = Kd >> 6;
    for (int T = 0; T < nt - 1; ++T) {
        const int bufv = T & 1, nb = bufv ^ 1;
        STAGE_A(nb, 0, T + 1); STAGE_A(nb, 1, T + 1);
        VM_(4); BAR_; FENCE_;
        READ_B(bufv, 0); READ_A8(bufv, 0);
        STAGE_B(nb, 0, T + 1); STAGE_B(nb, 1, T + 1);
        WAITL_; MFMA32_;
        READ_B(bufv, 1); READ_A8(bufv, 1);
        WAITL_; MFMA32_;
        BAR_;
    }
    {
        const int bufv = (nt - 1) & 1;
        VM_(0); BAR_; FENCE_;
        READ_B(bufv, 0); READ_A8(bufv, 0);
        WAITL_; MFMA32_;
        READ_B(bufv, 1); READ_A8(bufv, 1);
        WAITL_; MFMA32_;
    }

#undef STAGE_A
#undef STAGE_B
#undef LDA_
#undef LDB_
#undef FENCE_
#undef BAR_
#undef WAITL_
#undef VM_
#undef READ_B
#undef READ_A8
#undef MFMA32_

#pragma unroll
    for (int mf = 0; mf < 8; ++mf)
#pragma unroll
        for (int nf = 0; nf < 4; ++nf) {
            const int col = col0 + wn*64 + nf*16 + fr;
            const float bv = bias[col];
#pragma unroll
            for (int j = 0; j < 4; ++j) {
                const int row = row0 + mf*32 + wm*16 + fq*4 + j;
                float v = acc[mf][nf][j] + bv;
                if (EPI == 1) v = gelu_exact(v);
                C[(size_t)row*ldc + col] = f2bf(v);
            }
        }
}

// ============ fused h->bf16 conversion + pooling partials ============
__global__ __launch_bounds__(256)
void cvt_pool(const float* __restrict__ h, u16* __restrict__ hb,
              float* __restrict__ pp) {
    const int b = blockIdx.x, nc = blockIdx.y, t = threadIdx.x;
    const float* hp = h + ((size_t)b*N_ + (size_t)nc*8)*TD_;
    u16* op = hb + ((size_t)b*N_ + (size_t)nc*8)*TD_;
    f32x4 sum[5] = {};
    for (int r = 0; r < 8; ++r) {
        const float* rp = hp + (size_t)r*TD_;
        u16* orow = op + (size_t)r*TD_;
#pragma unroll
        for (int j = 0; j < 5; ++j) {
            const int c = (t + 256*j) << 2;
            f32x4 v = *(const f32x4*)(rp + c);
            sum[j] += v;
            u16x4 o = { f2bf(v[0]), f2bf(v[1]), f2bf(v[2]), f2bf(v[3]) };
            *(u16x4*)(orow + c) = o;
        }
    }
#pragma unroll
    for (int j = 0; j < 5; ++j) {
        const int c = (t + 256*j) << 2;
        *(f32x4*)(pp + ((size_t)b*128 + nc)*TD_ + c) = sum[j];
    }
}

__global__ void pool_reduce(const float* __restrict__ pp, float* __restrict__ pooled) {
    const int idx = blockIdx.x*256 + threadIdx.x;   // 40960
    const int b = idx / TD_, c = idx % TD_;
    float s = 0.f;
    for (int nc = 0; nc < 128; ++nc) s += pp[((size_t)b*128 + nc)*TD_ + c];
    pooled[idx] = s * (1.0f/N_);
}

// ============ weight transpose, batched over 5 adapters (grid.z) ============
__global__ __launch_bounds__(256)
void cvt_transpose5(Ptr5 W5, u16* __restrict__ WtBase, long wtStride,
                    int Kd, int Nd) {
    __shared__ float t[64][65];
    const float* W = W5.p[blockIdx.z];
    u16* Wt = WtBase + (size_t)blockIdx.z * wtStride;
    const int k0 = blockIdx.x * 64, n0 = blockIdx.y * 64;
    const int tid = threadIdx.x;
#pragma unroll
    for (int i = 0; i < 4; ++i) {
        int ch = tid + i*256;
        int r = ch >> 4, c4 = (ch & 15) << 2;
        f32x4 v = *(const f32x4*)(W + (size_t)(k0 + r)*Nd + n0 + c4);
        t[r][c4] = v[0]; t[r][c4+1] = v[1]; t[r][c4+2] = v[2]; t[r][c4+3] = v[3];
    }
    __syncthreads();
#pragma unroll
    for (int i = 0; i < 2; ++i) {
        int ch = tid + i*256;
        int nr = ch >> 3, c8 = (ch & 7) << 3;
        u16x8 o;
#pragma unroll
        for (int j = 0; j < 8; ++j) o[j] = f2bf(t[c8 + j][nr]);
        *(u16x8*)(Wt + (size_t)(n0 + nr)*Kd + k0 + c8) = o;
    }
}

// ============ LayerNorm in place (bf16), unit-indexed params ============
__global__ __launch_bounds__(256)
void ln_rows_u(u16* __restrict__ X, const float* __restrict__ gslab,
               const float* __restrict__ bslab, const int* __restrict__ units_a) {
    const int row = blockIdx.x, tid = threadIdx.x;
    const int ua = units_a[row >> 10];
    const float* g  = gslab + (size_t)ua*SD_;
    const float* bt = bslab + (size_t)ua*SD_;
    u16* rp = X + (size_t)row*SD_;
    const u16x8 v = ((const u16x8*)rp)[tid];
    float f[8]; float s = 0.f, s2 = 0.f;
#pragma unroll
    for (int j = 0; j < 8; ++j) { f[j] = bf2f(v[j]); s += f[j]; s2 += f[j]*f[j]; }
    __shared__ float sa[4], sb[4];
#pragma unroll
    for (int o = 32; o > 0; o >>= 1) { s += __shfl_down(s, o); s2 += __shfl_down(s2, o); }
    if ((tid & 63) == 0) { sa[tid >> 6] = s; sb[tid >> 6] = s2; }
    __syncthreads();
    s = sa[0]+sa[1]+sa[2]+sa[3]; s2 = sb[0]+sb[1]+sb[2]+sb[3];
    const float mean = s * (1.0f/SD_);
    const float inv  = rsqrtf(s2 * (1.0f/SD_) - mean*mean + 1e-5f);
    const int c0 = tid*8;
    u16x8 o;
#pragma unroll
    for (int j = 0; j < 8; ++j) o[j] = f2bf((f[j]-mean)*inv*g[c0+j] + bt[c0+j]);
    ((u16x8*)rp)[tid] = o;
}

// ============ q-projection: split-K parallel ============
__global__ __launch_bounds__(256)
void qp_part(Ptr5 q, Ptr5 wq, float* __restrict__ Sp) {
    __shared__ float qL[16][256];
    const int a = blockIdx.y, ks = blockIdx.z;
    const int c = blockIdx.x*256 + threadIdx.x;
    const int t = threadIdx.x;
    const float* Q = q.p[a];
    for (int i = t; i < 16*256; i += 256)
        qL[i >> 8][i & 255] = Q[(size_t)(i >> 8)*SD_ + ks*256 + (i & 255)];
    __syncthreads();
    const float* W = wq.p[a] + (size_t)(ks*256)*SD_ + c;
    float acc[16] = {};
    for (int i = 0; i < 256; i += 4) {
        const float w0 = W[(size_t)i*SD_];
        const float w1 = W[(size_t)(i+1)*SD_];
        const float w2 = W[(size_t)(i+2)*SD_];
        const float w3 = W[(size_t)(i+3)*SD_];
#pragma unroll
        for (int k = 0; k < 16; ++k) {
            f32x4 q4 = *(const f32x4*)&qL[k][i];
            acc[k] += q4[0]*w0 + q4[1]*w1 + q4[2]*w2 + q4[3]*w3;
        }
    }
#pragma unroll
    for (int k = 0; k < 16; ++k)
        Sp[((size_t)(a*8 + ks)*16 + k)*SD_ + c] = acc[k];
}

__global__ void qp_reduce(const float* __restrict__ Sp, Ptr5 bq, float* __restrict__ qp) {
    const int idx = blockIdx.x*256 + threadIdx.x;   // 163840
    const int a = idx >> 15, k = (idx >> 11) & 15, c = idx & 2047;
    float s = bq.p[a][c];
#pragma unroll
    for (int ks = 0; ks < 8; ++ks)
        s += Sp[((size_t)(a*8 + ks)*16 + k)*SD_ + c];
    qp[idx] = s;
}

// ============ fused scores + softmax -> P (f32) ============
__global__ __launch_bounds__(256)
void scores_sm(const u16* __restrict__ Kb, const float* __restrict__ qp,
               const int* __restrict__ units_a, float* __restrict__ P)
{
    __shared__ float sL[16][1024];
    __shared__ float qL[16][256];
    __shared__ float red[8];
    const int u = blockIdx.x >> 3, hh = blockIdx.x & 7;
    const int ua = units_a[u];
    const int t = threadIdx.x;
    for (int i = t; i < 16*256; i += 256)
        qL[i >> 8][i & 255] = qp[(size_t)(ua*16 + (i >> 8))*SD_ + hh*256 + (i & 255)];
    __syncthreads();
    const u16* Ku = Kb + (size_t)u*1024*SD_ + hh*256;
#pragma unroll
    for (int j = 0; j < 4; ++j) {
        const int n = t + j*256;
        const u16* kr = Ku + (size_t)n*SD_;
        float acc[16] = {};
        for (int d0 = 0; d0 < 256; d0 += 8) {
            u16x8 kv8 = *(const u16x8*)(kr + d0);
            float kf[8];
#pragma unroll
            for (int e = 0; e < 8; ++e) kf[e] = bf2f(kv8[e]);
#pragma unroll
            for (int k = 0; k < 16; ++k) {
                f32x4 q0 = *(const f32x4*)&qL[k][d0];
                f32x4 q1 = *(const f32x4*)&qL[k][d0+4];
                acc[k] += q0[0]*kf[0] + q0[1]*kf[1] + q0[2]*kf[2] + q0[3]*kf[3]
                        + q1[0]*kf[4] + q1[1]*kf[5] + q1[2]*kf[6] + q1[3]*kf[7];
            }
        }
#pragma unroll
        for (int k = 0; k < 16; ++k) sL[k][n] = acc[k] * 0.0625f;
    }
    __syncthreads();
    const int lane = t & 63, wv = t >> 6;
    for (int k = 0; k < 16; ++k) {
        float v0 = sL[k][t], v1 = sL[k][t+256], v2 = sL[k][t+512], v3 = sL[k][t+768];
        float mx = fmaxf(fmaxf(v0,v1), fmaxf(v2,v3));
#pragma unroll
        for (int o = 1; o < 64; o <<= 1) mx = fmaxf(mx, __shfl_xor(mx, o));
        if (lane == 0) red[wv] = mx;
        __syncthreads();
        mx = fmaxf(fmaxf(red[0],red[1]), fmaxf(red[2],red[3]));
        float e0 = expf(v0-mx), e1 = expf(v1-mx), e2 = expf(v2-mx), e3 = expf(v3-mx);
        float s = e0+e1+e2+e3;
#pragma unroll
        for (int o = 1; o < 64; o <<= 1) s += __shfl_xor(s, o);
        if (lane == 0) red[4+wv] = s;
        __syncthreads();
        s = red[4]+red[5]+red[6]+red[7];
        const float inv = 1.0f/s;
        float* Pr = P + ((size_t)(u*8+hh)*16 + k)*1024;
        Pr[t]=e0*inv; Pr[t+256]=e1*inv; Pr[t+512]=e2*inv; Pr[t+768]=e3*inv;
        __syncthreads();
    }
}

// ============ ctx: P @ V -> ctxb (bf16) ============
__global__ __launch_bounds__(256)
void ctx_u(const u16* __restrict__ Vb, const float* __restrict__ P,
           u16* __restrict__ ctxb)
{
    __shared__ float pL[16][1024];
    const int u = blockIdx.x >> 3, hh = blockIdx.x & 7;
    const int t = threadIdx.x;
    const float* Pu = P + (size_t)(u*8+hh)*16*1024;
    for (int i = t; i < 16*1024/4; i += 256)
        ((f32x4*)&pL[0][0])[i] = ((const f32x4*)Pu)[i];
    __syncthreads();
    const u16* Vu = Vb + (size_t)u*1024*SD_ + hh*256 + t;
    float acc[16] = {};
    for (int n = 0; n < 1024; n += 4) {
        float vv0 = bf2f(Vu[(size_t)n*SD_]);
        float vv1 = bf2f(Vu[(size_t)(n+1)*SD_]);
        float vv2 = bf2f(Vu[(size_t)(n+2)*SD_]);
        float vv3 = bf2f(Vu[(size_t)(n+3)*SD_]);
#pragma unroll
        for (int k = 0; k < 16; ++k) {
            f32x4 p4 = *(const f32x4*)&pL[k][n];
            acc[k] += p4[0]*vv0 + p4[1]*vv1 + p4[2]*vv2 + p4[3]*vv3;
        }
    }
#pragma unroll
    for (int k = 0; k < 16; ++k)
        ctxb[(size_t)u*16*SD_ + k*SD_ + hh*256 + t] = f2bf(acc[k]);
}

// ============ ow-GEMM: split-K x4 ============
__global__ __launch_bounds__(256)
void gemm_ow_part(const u16* __restrict__ ctxb, const u16* __restrict__ Bslab,
                  const int* __restrict__ units_a, float* __restrict__ ctx2p)
{
    const int u = blockIdx.y, ua = units_a[u], ks = blockIdx.z;
    const int wave = threadIdx.x >> 6, lane = threadIdx.x & 63;
    const int col0 = blockIdx.x*256 + wave*64;
    const u16* A  = ctxb + (size_t)u*16*SD_;
    const u16* Bt = Bslab + (size_t)ua*SD_*SD_;
    const int fr = lane & 15, fk8 = (lane >> 4) << 3;
    f32x4 acc[4] = {};
    const int kbase = ks*512;
    for (int k0 = kbase; k0 < kbase + 512; k0 += 32) {
        bf16x8 af = *(const bf16x8*)(A + (size_t)fr*SD_ + k0 + fk8);
#pragma unroll
        for (int n = 0; n < 4; ++n) {
            bf16x8 bf8 = *(const bf16x8*)(Bt + (size_t)(col0 + n*16 + fr)*SD_ + k0 + fk8);
            acc[n] = __builtin_amdgcn_mfma_f32_16x16x32_bf16(af, bf8, acc[n], 0, 0, 0);
        }
    }
    const int fq = lane >> 4;
#pragma unroll
    for (int n = 0; n < 4; ++n)
#pragma unroll
        for (int j = 0; j < 4; ++j) {
            const int row = fq*4 + j, col = col0 + n*16 + fr;
            ctx2p[(((size_t)ks*24 + u)*16 + row)*SD_ + col] = acc[n][j];
        }
}

__global__ void gemm_ow_reduce(const float* __restrict__ ctx2p,
                               const float* __restrict__ biasSlab,
                               const int* __restrict__ units_a,
                               float* __restrict__ ctx2) {
    const int idx = blockIdx.x*256 + threadIdx.x;   // 786432
    const int u = idx / (16*SD_);
    const int rem = idx % (16*SD_);
    const int col = rem % SD_;
    float s = biasSlab[units_a[u]*SD_ + col];
#pragma unroll
    for (int ks = 0; ks < 4; ++ks)
        s += ctx2p[((size_t)ks*24*16*SD_) + (size_t)u*16*SD_ + rem];
    ctx2[idx] = s;
}

// ============ final LN ============
__global__ __launch_bounds__(256)
void ln_post_u(const float* __restrict__ ctx2, const float* __restrict__ qslab,
               const float* __restrict__ pgs, const float* __restrict__ pbs,
               const int* __restrict__ units_a, const int* __restrict__ units_b,
               float* __restrict__ out, float* __restrict__ cspec)
{
    const int k = blockIdx.x, u = blockIdx.y, tid = threadIdx.x;
    const int ua = units_a[u];
    const float* ip = ctx2 + ((size_t)u*16 + k)*SD_;
    const float* qr = qslab + ((size_t)ua*16 + k)*SD_;
    const float* g  = pgs + (size_t)ua*SD_;
    const float* bt = pbs + (size_t)ua*SD_;
    float f[8]; float s = 0.f, s2 = 0.f;
#pragma unroll
    for (int j = 0; j < 8; ++j) {
        const int c = tid + j*256;
        f[j] = ip[c] + qr[c];
        s += f[j]; s2 += f[j]*f[j];
    }
    __shared__ float sa[4], sb[4];
#pragma unroll
    for (int o = 32; o > 0; o >>= 1) { s += __shfl_down(s, o); s2 += __shfl_down(s2, o); }
    if ((tid & 63) == 0) { sa[tid >> 6] = s; sb[tid >> 6] = s2; }
    __syncthreads();
    s = sa[0]+sa[1]+sa[2]+sa[3]; s2 = sb[0]+sb[1]+sb[2]+sb[3];
    const float mean = s * (1.0f/SD_);
    const float inv  = rsqrtf(s2 * (1.0f/SD_) - mean*mean + 1e-5f);
    float* op = (u < 8) ? out + ((size_t)units_b[u]*32 + k)*SD_
                        : cspec + ((size_t)(u-8)*16 + k)*SD_;
#pragma unroll
    for (int j = 0; j < 8; ++j) { const int c = tid + j*256; op[c] = (f[j]-mean)*inv*g[c] + bt[c]; }
}

// ============ router tail ============
__global__ __launch_bounds__(256)
void rmlp_part(const float* __restrict__ pooled, const float* __restrict__ w1,
               float* __restrict__ rp) {
    const int c = blockIdx.x*256 + threadIdx.x;
    const int b = blockIdx.y, is = blockIdx.z;
    const float* pr = pooled + b*TD_ + is*512;
    const float* W = w1 + (size_t)(is*512)*512 + c;
    float s = 0.f;
    for (int i = 0; i < 512; ++i) s += pr[i] * W[(size_t)i*512];
    rp[(b*10 + is)*512 + c] = s;
}
__global__ void rmlp_reduce(const float* __restrict__ rp, const float* __restrict__ b1,
                            float* __restrict__ hid) {
    const int idx = blockIdx.x*256 + threadIdx.x;
    const int b = idx >> 9, c = idx & 511;
    float s = b1[c];
#pragma unroll
    for (int is = 0; is < 10; ++is) s += rp[(b*10 + is)*512 + c];
    hid[idx] = gelu_exact(s);
}

__global__ void router_final(const float* __restrict__ hid, const float* __restrict__ w2,
                             const float* __restrict__ b2, float* __restrict__ probs,
                             int* __restrict__ widx, float* __restrict__ wval,
                             int* __restrict__ units_a, int* __restrict__ units_b) {
    __shared__ float lg[8][4];
    __shared__ int sw[16];
    const int tid = threadIdx.x;
    if (tid < 32) {
        const int b = tid >> 2, m = tid & 3;
        float s = b2[m];
        const float* hr = hid + b*512;
        for (int i = 0; i < 512; ++i) s += hr[i]*w2[i*4 + m];
        lg[b][m] = s;
    }
    __syncthreads();
    if (tid < 8) {
        const int b = tid;
        const float l0=lg[b][0], l1=lg[b][1], l2=lg[b][2], l3=lg[b][3];
        const float mx = fmaxf(fmaxf(l0,l1),fmaxf(l2,l3));
        const float e0=expf(l0-mx), e1=expf(l1-mx), e2=expf(l2-mx), e3=expf(l3-mx);
        const float s = e0+e1+e2+e3;
        float p[4] = {e0/s, e1/s, e2/s, e3/s};
        probs[b*4+0]=p[0]; probs[b*4+1]=p[1]; probs[b*4+2]=p[2]; probs[b*4+3]=p[3];
        int i0 = 0;
        for (int m = 1; m < 4; ++m) if (p[m] > p[i0]) i0 = m;
        int i1 = -1;
        for (int m = 0; m < 4; ++m) if (m != i0 && (i1 < 0 || p[m] > p[i1])) i1 = m;
        const float w0 = p[i0], w1 = p[i1], ws = w0 + w1 + 1e-8f;
        widx[b*2]=i0; widx[b*2+1]=i1;
        wval[b*2]=w0/ws; wval[b*2+1]=w1/ws;
        sw[b*2]=i0; sw[b*2+1]=i1;
    }
    __syncthreads();
    if (tid < 24) {
        units_a[tid] = (tid < 8) ? 0 : sw[tid-8] + 1;
        units_b[tid] = (tid < 8) ? tid : ((tid-8) >> 1);
    }
}

__global__ void combine_k(const float* __restrict__ cspec, const int* __restrict__ widx,
                          const float* __restrict__ wval, float* __restrict__ out) {
    const int i = blockIdx.x*256 + threadIdx.x;
    const int c4 = i & 511;
    const int k  = (i >> 9) & 15;
    const int b  = i >> 13;
    const float w0 = wval[b*2], w1 = wval[b*2+1];
    const f32x4 v0 = ((const f32x4*)cspec)[(size_t)((2*b)  *16 + k)*512 + c4];
    const f32x4 v1 = ((const f32x4*)cspec)[(size_t)((2*b+1)*16 + k)*512 + c4];
    ((f32x4*)out)[(size_t)(b*32 + 16 + k)*512 + c4] = v0*w0 + v1*w1;
}

// ============ fused pack: bias_dw (5120) | qslab (163840) | slab8 (81920) ====
__global__ void pack_all(Ptr5 db5, Ptr5 q5, Ptr40 s8, float* __restrict__ bias_dw,
                         float* __restrict__ qslab, float* __restrict__ slab8) {
    int i = blockIdx.x*256 + threadIdx.x;   // 250880 total
    if (i < 5120) {
        bias_dw[i] = db5.p[i >> 10][i & 1023];
    } else if (i < 5120 + 163840) {
        int j = i - 5120;
        qslab[j] = q5.p[j / 32768][j % 32768];
    } else if (i < 5120 + 163840 + 81920) {
        int j = i - 5120 - 163840;
        int slab = j / 10240, rem = j % 10240;
        slab8[j] = s8.p[slab][rem / 2048][rem % 2048];
    }
}

// ============ host ============
extern "C" void kernel_launch(void* const* d_in, const int* in_sizes, int n_in,
                              void* d_out, int out_size, void* d_ws, size_t ws_size,
                              hipStream_t stream) {
    if (ws_size < 300300000ULL) return;

    const float* h = (const float*)d_in[0];
    const float* G[17]; const float* Sx[17];
    for (int i = 0; i < 17; ++i) { G[i] = (const float*)d_in[1+i]; Sx[i] = (const float*)d_in[18+i]; }
    const float* r_w1 = (const float*)d_in[35];
    const float* r_b1 = (const float*)d_in[36];
    const float* r_w2 = (const float*)d_in[37];
    const float* r_b2 = (const float*)d_in[38];

    static const size_t str[17] = {
        (size_t)TD_*BD_, BD_, (size_t)BD_*SD_, SD_, SD_, SD_, (size_t)K_*SD_,
        (size_t)SD_*SD_, (size_t)SD_*SD_, (size_t)SD_*SD_, (size_t)SD_*SD_,
        SD_, SD_, SD_, SD_, SD_, SD_ };
    auto P = [&](int pi, int a) -> const float* {
        return (a == 0) ? G[pi] : Sx[pi] + (size_t)(a-1)*str[pi];
    };

    char* w = (char*)d_ws;
    const size_t R0 = 0, R1 = 100663296, R2 = 201326592, R3 = 251658240, TAIL = 293601280;
    u16*   h_bf  = (u16*)(w + R0);
    u16*   X     = (u16*)(w + R0);
    u16*   wt_dw = (u16*)(w + R1);
    u16*   Kbuf  = (u16*)(w + R1);
    u16*   X1    = (u16*)(w + R2);
    u16*   wt_v  = (u16*)(w + R2);
    u16*   wt_ow = (u16*)(w + R2);
    u16*   wt_uw = (u16*)(w + R3);
    u16*   wt_k  = (u16*)(w + R3);
    u16*   ctxb  = (u16*)(w + R3);
    float* ctx2  = (float*)(w + R3 + 1572864);
    float* cspec = (float*)(w + R3 + 4718592);
    float* Pbuf  = (float*)(w + R3 + 6815744);
    float* ctx2p = (float*)(w + R3 + 19398656);
    float* qpp   = (float*)(w + R2);
    float* poolp = (float*)(w + R2 + 12582912);
    float* routp = (float*)(w + R2 + 33554432);
    float* qp_all  = (float*)(w + TAIL);
    float* qslab   = (float*)(w + TAIL + 655360);
    float* bias_dw = (float*)(w + TAIL + 1310720);
    float* slab8   = (float*)(w + TAIL + 1331200);
    float* pooled  = (float*)(w + TAIL + 1658880);
    float* hid     = (float*)(w + TAIL + 1822720);
    int*   widx    = (int*)  (w + TAIL + 1839104);
    float* wval    = (float*)(w + TAIL + 1839168);
    int*   units_a = (int*)  (w + TAIL + 1839232);
    int*   units_b = (int*)  (w + TAIL + 1839328);

    float* bias_uw = slab8;
    float* bias_k  = slab8 + 1*5*SD_;
    float* bias_v  = slab8 + 2*5*SD_;
    float* bias_ow = slab8 + 3*5*SD_;
    float* lng     = slab8 + 4*5*SD_;
    float* lnb     = slab8 + 5*5*SD_;
    float* pgs     = slab8 + 6*5*SD_;
    float* pbs     = slab8 + 7*5*SD_;

    float* out = (float*)d_out;

    // ---- fused conversion + pooling, then router ----
    cvt_pool<<<dim3(8, 128), 256, 0, stream>>>(h, h_bf, poolp);
    pool_reduce<<<160, 256, 0, stream>>>(poolp, pooled);
    rmlp_part<<<dim3(2, 8, 10), 256, 0, stream>>>(pooled, r_w1, routp);
    rmlp_reduce<<<16, 256, 0, stream>>>(routp, r_b1, hid);
    router_final<<<1, 64, 0, stream>>>(hid, r_w2, r_b2, out + 524288, widx, wval, units_a, units_b);

    // ---- q projections (split-K) + fused packs ----
    Ptr5 q5, wq5, bq5, db5;
    for (int a = 0; a < 5; ++a) { q5.p[a]=P(6,a); wq5.p[a]=P(7,a); bq5.p[a]=P(11,a); db5.p[a]=P(1,a); }
    qp_part<<<dim3(8, 5, 8), 256, 0, stream>>>(q5, wq5, qpp);
    qp_reduce<<<640, 256, 0, stream>>>(qpp, bq5, qp_all);
    Ptr40 s8;
    static const int slab_pi[8] = {3, 12, 13, 14, 4, 5, 15, 16};
    for (int si = 0; si < 8; ++si)
        for (int a = 0; a < 5; ++a) s8.p[si][a] = P(slab_pi[si], a);
    pack_all<<<981, 256, 0, stream>>>(db5, q5, s8, bias_dw, qslab, slab8);

    // ---- upfront transposes (batched over adapters) ----
    Ptr5 dw5, uw5, k5, v5, ow5;
    for (int a = 0; a < 5; ++a) {
        dw5.p[a] = P(0,a); uw5.p[a] = P(2,a);
        k5.p[a] = P(8,a); v5.p[a] = P(9,a); ow5.p[a] = P(10,a);
    }
    cvt_transpose5<<<dim3(TD_/64, BD_/64, 5), 256, 0, stream>>>(dw5, wt_dw, (long)BD_*TD_, TD_, BD_);
    cvt_transpose5<<<dim3(BD_/64, SD_/64, 5), 256, 0, stream>>>(uw5, wt_uw, (long)SD_*BD_, BD_, SD_);

    // ---- down-proj (gelu): gemm128 @4 blocks/CU ----
    gemm128<1, 0><<<dim3(8, 8, 24), 256, 0, stream>>>(
        h_bf, wt_dw, (long)BD_*TD_, bias_dw, BD_, X1, BD_, (long)1024*BD_, TD_, units_a, units_b);

    // ---- up-proj: gemm256 (r12 config) ----
    gemm256<0, 1><<<dim3(4, 8, 24), 512, 0, stream>>>(
        X1, wt_uw, (long)SD_*BD_, bias_uw, SD_, X, SD_, (long)1024*SD_, BD_, units_a, units_b);

    // ---- LN in place ----
    ln_rows_u<<<24*1024, 256, 0, stream>>>(X, lng, lnb, units_a);

    // ---- transposes for K/V (batched) ----
    cvt_transpose5<<<dim3(SD_/64, SD_/64, 5), 256, 0, stream>>>(k5, wt_k, (long)SD_*SD_, SD_, SD_);
    cvt_transpose5<<<dim3(SD_/64, SD_/64, 5), 256, 0, stream>>>(v5, wt_v, (long)SD_*SD_, SD_, SD_);

    // ---- K projection: gemm256 ----
    gemm256<0, 1><<<dim3(4, 8, 24), 512, 0, stream>>>(
        X, wt_k, (long)SD_*SD_, bias_k, SD_, Kbuf, SD_, (long)1024*SD_, SD_, units_a, units_b);

    // ---- scores + softmax ----
    scores_sm<<<24*8, 256, 0, stream>>>(Kbuf, qp_all, units_a, Pbuf);

    // ---- V projection ----
    gemm256<0, 1><<<dim3(4, 8, 24), 512, 0, stream>>>(
        X, wt_v, (long)SD_*SD_, bias_v, SD_, Kbuf, SD_, (long)1024*SD_, SD_, units_a, units_b);

    // ---- ow transpose (batched) ----
    cvt_transpose5<<<dim3(SD_/64, SD_/64, 5), 256, 0, stream>>>(ow5, wt_ow, (long)SD_*SD_, SD_, SD_);

    // ---- ctx = P @ V ----
    ctx_u<<<24*8, 256, 0, stream>>>(Kbuf, Pbuf, ctxb);

    // ---- output projection: split-K x4 + reduce ----
    gemm_ow_part<<<dim3(8, 24, 4), 256, 0, stream>>>(ctxb, wt_ow, units_a, ctx2p);
    gemm_ow_reduce<<<3072, 256, 0, stream>>>(ctx2p, bias_ow, units_a, ctx2);

    // ---- final LN + combine ----
    ln_post_u<<<dim3(16, 24), 256, 0, stream>>>(ctx2, qslab, pgs, pbs, units_a, units_b, out, cspec);
    combine_k<<<256, 256, 0, stream>>>(cspec, widx, wval, out);
}

// Round 18
// 1308.594 us; speedup vs baseline: 1.2896x; 1.0044x over previous
//
#include <hip/hip_runtime.h>
#include <hip/hip_bf16.h>

#define B_   8
#define N_   1024
#define TD_  5120
#define SD_  2048
#define BD_  1024
#define K_   16
#define H_   8

typedef unsigned short u16;
typedef __attribute__((ext_vector_type(8))) short bf16x8;
typedef __attribute__((ext_vector_type(4))) float f32x4;
typedef __attribute__((ext_vector_type(8))) u16 u16x8;
typedef __attribute__((ext_vector_type(4))) u16 u16x4;

__device__ __forceinline__ float bf2f(u16 u) {
    union { unsigned int i; float f; } x; x.i = ((unsigned)u) << 16; return x.f;
}
__device__ __forceinline__ u16 f2bf(float f) {
    union { float f; unsigned int i; } x; x.f = f;
    unsigned int i = x.i;
    return (u16)((i + 0x7fffu + ((i >> 16) & 1u)) >> 16);
}
__device__ __forceinline__ float gelu_exact(float v) {
    return 0.5f * v * (1.0f + erff(v * 0.70710678118654752f));
}
__device__ __forceinline__ void gload_lds16(const void* g, void* l) {
    __builtin_amdgcn_global_load_lds(
        (const __attribute__((address_space(1))) unsigned int*)g,
        (__attribute__((address_space(3))) unsigned int*)l, 16, 0, 0);
}

struct Ptr5 { const float* p[5]; };
struct Ptr40 { const float* p[8][5]; };

// ============ 128x128 m97-style GEMM, BK=64, single-buffer, 4 blocks/CU ====
template<int EPI, int AMODE>
__global__ __launch_bounds__(256, 4)
void gemm128(const u16* __restrict__ Abase,
             const u16* __restrict__ Bbase, long bStride,
             const float* __restrict__ biasBase, int biasStride,
             u16* __restrict__ Cbase, int ldc, long cStride, int Kd,
             const int* __restrict__ units_a, const int* __restrict__ units_b)
{
    __shared__ char lds[32768];           // A 16 KB | B 16 KB
    const int u = blockIdx.z;
    const int ua = units_a[u];
    const int ub = (AMODE == 0) ? units_b[u] : u;
    const u16* A  = Abase + (size_t)ub * 1024 * Kd;
    const u16* Bt = Bbase + (size_t)ua * bStride;
    const float* bias = biasBase + (size_t)ua * biasStride;
    u16* C = Cbase + (size_t)u * cStride;

    const int tid  = threadIdx.x;
    const int wave = tid >> 6, lane = tid & 63;
    const int wm = wave >> 1, wn = wave & 1;
    const int row0 = blockIdx.x * 128, col0 = blockIdx.y * 128;

    const int srow = tid >> 3;                       // 0..31
    const int scol = ((tid & 7) ^ (srow & 7)) << 3;  // elems
    const char* aSrc = (const char*)(A  + (size_t)(row0 + srow) * Kd + scol);
    const char* bSrc = (const char*)(Bt + (size_t)(col0 + srow) * Kd + scol);
    const int ldsW = wave * 1024;

    const int fr = lane & 15, fq = lane >> 4;
    const int kl  = fq << 4;
    const int swz = (fr & 7) << 4;

    f32x4 acc[4][4] = {};

#define LDA_(mf, kk) (*(const bf16x8*)(lds + \
    (wm*64 + (mf)*16 + fr)*128 + ((((kk)*64) + kl) ^ swz)))
#define LDB_(nf, kk) (*(const bf16x8*)(lds + 16384 + \
    (wn*64 + (nf)*16 + fr)*128 + ((((kk)*64) + kl) ^ swz)))

    const int nt = Kd >> 6;
    for (int T = 0; T < nt; ++T) {
        const size_t kb = (size_t)T << 7;
#pragma unroll
        for (int l = 0; l < 4; ++l)
            gload_lds16(aSrc + (size_t)(l*32)*Kd*2 + kb, lds + l*4096 + ldsW);
#pragma unroll
        for (int l = 0; l < 4; ++l)
            gload_lds16(bSrc + (size_t)(l*32)*Kd*2 + kb, lds + 16384 + l*4096 + ldsW);
        asm volatile("s_waitcnt vmcnt(0)" ::: "memory");
        __syncthreads();
#pragma unroll
        for (int kk = 0; kk < 2; ++kk) {
            bf16x8 aF[4], bF[4];
#pragma unroll
            for (int i = 0; i < 4; ++i) aF[i] = LDA_(i, kk);
#pragma unroll
            for (int n = 0; n < 4; ++n) bF[n] = LDB_(n, kk);
#pragma unroll
            for (int i = 0; i < 4; ++i)
#pragma unroll
                for (int n = 0; n < 4; ++n)
                    acc[i][n] = __builtin_amdgcn_mfma_f32_16x16x32_bf16(
                        aF[i], bF[n], acc[i][n], 0, 0, 0);
        }
        __syncthreads();
    }

#undef LDA_
#undef LDB_

#pragma unroll
    for (int mf = 0; mf < 4; ++mf)
#pragma unroll
        for (int nf = 0; nf < 4; ++nf) {
            const int col = col0 + wn*64 + nf*16 + fr;
            const float bv = bias[col];
#pragma unroll
            for (int j = 0; j < 4; ++j) {
                const int row = row0 + wm*64 + mf*16 + fq*4 + j;
                float v = acc[mf][nf][j] + bv;
                if (EPI == 1) v = gelu_exact(v);
                C[(size_t)row*ldc + col] = f2bf(v);
            }
        }
}

// ============ 256x256 counted-vmcnt GEMM (r7/r12, validated) ============
template<int EPI, int AMODE>
__global__ __launch_bounds__(512, 2)
void gemm256(const u16* __restrict__ Abase,
             const u16* __restrict__ Bbase, long bStride,
             const float* __restrict__ biasBase, int biasStride,
             u16* __restrict__ Cbase, int ldc, long cStride, int Kd,
             const int* __restrict__ units_a, const int* __restrict__ units_b)
{
    __shared__ char lds[131072];
    const int u = blockIdx.z;
    const int ua = units_a[u];
    const int ub = (AMODE == 0) ? units_b[u] : u;
    const u16* A  = Abase + (size_t)ub * 1024 * Kd;
    const u16* Bt = Bbase + (size_t)ua * bStride;
    const float* bias = biasBase + (size_t)ua * biasStride;
    u16* C = Cbase + (size_t)u * cStride;

    const int tid  = threadIdx.x;
    const int wave = tid >> 6, lane = tid & 63;
    const int wm = wave >> 2, wn = wave & 3;
    const int row0 = blockIdx.x * 256, col0 = blockIdx.y * 256;

    const int srow = tid >> 3;
    const int scol = ((tid & 7) ^ ((tid >> 3) & 7)) << 3;
    const char* aSrc = (const char*)(A  + (size_t)(row0 + srow) * Kd + scol);
    const char* bSrc = (const char*)(Bt + (size_t)(col0 + srow) * Kd + scol);
    const int ldsW = wave * 1024;

    const int fr = lane & 15, fq = lane >> 4;
    const int kl  = fq << 4;
    const int swz = (fr & 7) << 4;

    f32x4 acc[8][4] = {};
    bf16x8 aF[8], bF[4];

#define STAGE_A(bufv, hh, kt) do { \
    const char* s_ = aSrc + ((size_t)((hh)*128) * Kd + (size_t)(kt) * 64) * 2; \
    char* d_ = lds + (bufv)*65536 + (hh)*16384 + ldsW; \
    gload_lds16(s_, d_); \
    gload_lds16(s_ + (size_t)64 * Kd * 2, d_ + 8192); } while(0)
#define STAGE_B(bufv, hh, kt) do { \
    const char* s_ = bSrc + ((size_t)((hh)*128) * Kd + (size_t)(kt) * 64) * 2; \
    char* d_ = lds + (bufv)*65536 + 32768 + (hh)*16384 + ldsW; \
    gload_lds16(s_, d_); \
    gload_lds16(s_ + (size_t)64 * Kd * 2, d_ + 8192); } while(0)

#define LDA_(bufv, mf, kk) (*(const bf16x8*)(lds + (bufv)*65536 + \
    ((mf)*32 + wm*16 + fr)*128 + ((((kk)*64) + kl) ^ swz)))
#define LDB_(bufv, nf, kk) (*(const bf16x8*)(lds + (bufv)*65536 + 32768 + \
    (wn*64 + (nf)*16 + fr)*128 + ((((kk)*64) + kl) ^ swz)))

#define FENCE_ asm volatile("" ::: "memory")
#define BAR_   __builtin_amdgcn_s_barrier()
#define WAITL_ asm volatile("s_waitcnt lgkmcnt(0)" ::: "memory")
#define VM_(n) asm volatile("s_waitcnt vmcnt(" #n ")" ::: "memory")

#define READ_B(bufv, kk) { _Pragma("unroll") \
    for (int n_ = 0; n_ < 4; ++n_) bF[n_] = LDB_(bufv, n_, kk); }
#define READ_A8(bufv, kk) { _Pragma("unroll") \
    for (int i_ = 0; i_ < 8; ++i_) aF[i_] = LDA_(bufv, i_, kk); }
#define MFMA32_ { __builtin_amdgcn_s_setprio(1); \
    _Pragma("unroll") for (int i_ = 0; i_ < 8; ++i_) { \
      _Pragma("unroll") for (int n_ = 0; n_ < 4; ++n_) \
        acc[i_][n_] = __builtin_amdgcn_mfma_f32_16x16x32_bf16( \
            aF[i_], bF[n_], acc[i_][n_], 0, 0, 0); } \
    __builtin_amdgcn_s_setprio(0); }

    STAGE_A(0, 0, 0); STAGE_A(0, 1, 0);
    STAGE_B(0, 0, 0); STAGE_B(0, 1, 0);

    const int nt = Kd >> 6;
    for (int T = 0; T < nt - 1; ++T) {
        const int bufv = T & 1, nb = bufv ^ 1;
        STAGE_A(nb, 0, T + 1); STAGE_A(nb, 1, T + 1);
        VM_(4); BAR_; FENCE_;
        READ_B(bufv, 0); READ_A8(bufv, 0);
        STAGE_B(nb, 0, T + 1); STAGE_B(nb, 1, T + 1);
        WAITL_; MFMA32_;
        READ_B(bufv, 1); READ_A8(bufv, 1);
        WAITL_; MFMA32_;
        BAR_;
    }
    {
        const int bufv = (nt - 1) & 1;
        VM_(0); BAR_; FENCE_;
        READ_B(bufv, 0); READ_A8(bufv, 0);
        WAITL_; MFMA32_;
        READ_B(bufv, 1); READ_A8(bufv, 1);
        WAITL_; MFMA32_;
    }

#undef STAGE_A
#undef STAGE_B
#undef LDA_
#undef LDB_
#undef FENCE_
#undef BAR_
#undef WAITL_
#undef VM_
#undef READ_B
#undef READ_A8
#undef MFMA32_

#pragma unroll
    for (int mf = 0; mf < 8; ++mf)
#pragma unroll
        for (int nf = 0; nf < 4; ++nf) {
            const int col = col0 + wn*64 + nf*16 + fr;
            const float bv = bias[col];
#pragma unroll
            for (int j = 0; j < 4; ++j) {
                const int row = row0 + mf*32 + wm*16 + fq*4 + j;
                float v = acc[mf][nf][j] + bv;
                if (EPI == 1) v = gelu_exact(v);
                C[(size_t)row*ldc + col] = f2bf(v);
            }
        }
}

// ============ fused h->bf16 conversion + pooling partials ============
__global__ __launch_bounds__(256)
void cvt_pool(const float* __restrict__ h, u16* __restrict__ hb,
              float* __restrict__ pp) {
    const int b = blockIdx.x, nc = blockIdx.y, t = threadIdx.x;
    const float* hp = h + ((size_t)b*N_ + (size_t)nc*8)*TD_;
    u16* op = hb + ((size_t)b*N_ + (size_t)nc*8)*TD_;
    f32x4 sum[5] = {};
    for (int r = 0; r < 8; ++r) {
        const float* rp = hp + (size_t)r*TD_;
        u16* orow = op + (size_t)r*TD_;
#pragma unroll
        for (int j = 0; j < 5; ++j) {
            const int c = (t + 256*j) << 2;
            f32x4 v = *(const f32x4*)(rp + c);
            sum[j] += v;
            u16x4 o = { f2bf(v[0]), f2bf(v[1]), f2bf(v[2]), f2bf(v[3]) };
            *(u16x4*)(orow + c) = o;
        }
    }
#pragma unroll
    for (int j = 0; j < 5; ++j) {
        const int c = (t + 256*j) << 2;
        *(f32x4*)(pp + ((size_t)b*128 + nc)*TD_ + c) = sum[j];
    }
}

__global__ void pool_reduce(const float* __restrict__ pp, float* __restrict__ pooled) {
    const int idx = blockIdx.x*256 + threadIdx.x;   // 40960
    const int b = idx / TD_, c = idx % TD_;
    float s = 0.f;
    for (int nc = 0; nc < 128; ++nc) s += pp[((size_t)b*128 + nc)*TD_ + c];
    pooled[idx] = s * (1.0f/N_);
}

// ============ weight transpose, batched over 5 adapters (grid.z) ============
__global__ __launch_bounds__(256)
void cvt_transpose5(Ptr5 W5, u16* __restrict__ WtBase, long wtStride,
                    int Kd, int Nd) {
    __shared__ float t[64][65];
    const float* W = W5.p[blockIdx.z];
    u16* Wt = WtBase + (size_t)blockIdx.z * wtStride;
    const int k0 = blockIdx.x * 64, n0 = blockIdx.y * 64;
    const int tid = threadIdx.x;
#pragma unroll
    for (int i = 0; i < 4; ++i) {
        int ch = tid + i*256;
        int r = ch >> 4, c4 = (ch & 15) << 2;
        f32x4 v = *(const f32x4*)(W + (size_t)(k0 + r)*Nd + n0 + c4);
        t[r][c4] = v[0]; t[r][c4+1] = v[1]; t[r][c4+2] = v[2]; t[r][c4+3] = v[3];
    }
    __syncthreads();
#pragma unroll
    for (int i = 0; i < 2; ++i) {
        int ch = tid + i*256;
        int nr = ch >> 3, c8 = (ch & 7) << 3;
        u16x8 o;
#pragma unroll
        for (int j = 0; j < 8; ++j) o[j] = f2bf(t[c8 + j][nr]);
        *(u16x8*)(Wt + (size_t)(n0 + nr)*Kd + k0 + c8) = o;
    }
}

// ============ LayerNorm in place (bf16), unit-indexed params ============
__global__ __launch_bounds__(256)
void ln_rows_u(u16* __restrict__ X, const float* __restrict__ gslab,
               const float* __restrict__ bslab, const int* __restrict__ units_a) {
    const int row = blockIdx.x, tid = threadIdx.x;
    const int ua = units_a[row >> 10];
    const float* g  = gslab + (size_t)ua*SD_;
    const float* bt = bslab + (size_t)ua*SD_;
    u16* rp = X + (size_t)row*SD_;
    const u16x8 v = ((const u16x8*)rp)[tid];
    float f[8]; float s = 0.f, s2 = 0.f;
#pragma unroll
    for (int j = 0; j < 8; ++j) { f[j] = bf2f(v[j]); s += f[j]; s2 += f[j]*f[j]; }
    __shared__ float sa[4], sb[4];
#pragma unroll
    for (int o = 32; o > 0; o >>= 1) { s += __shfl_down(s, o); s2 += __shfl_down(s2, o); }
    if ((tid & 63) == 0) { sa[tid >> 6] = s; sb[tid >> 6] = s2; }
    __syncthreads();
    s = sa[0]+sa[1]+sa[2]+sa[3]; s2 = sb[0]+sb[1]+sb[2]+sb[3];
    const float mean = s * (1.0f/SD_);
    const float inv  = rsqrtf(s2 * (1.0f/SD_) - mean*mean + 1e-5f);
    const int c0 = tid*8;
    u16x8 o;
#pragma unroll
    for (int j = 0; j < 8; ++j) o[j] = f2bf((f[j]-mean)*inv*g[c0+j] + bt[c0+j]);
    ((u16x8*)rp)[tid] = o;
}

// ============ q-projection: split-K parallel ============
__global__ __launch_bounds__(256)
void qp_part(Ptr5 q, Ptr5 wq, float* __restrict__ Sp) {
    __shared__ float qL[16][256];
    const int a = blockIdx.y, ks = blockIdx.z;
    const int c = blockIdx.x*256 + threadIdx.x;
    const int t = threadIdx.x;
    const float* Q = q.p[a];
    for (int i = t; i < 16*256; i += 256)
        qL[i >> 8][i & 255] = Q[(size_t)(i >> 8)*SD_ + ks*256 + (i & 255)];
    __syncthreads();
    const float* W = wq.p[a] + (size_t)(ks*256)*SD_ + c;
    float acc[16] = {};
    for (int i = 0; i < 256; i += 4) {
        const float w0 = W[(size_t)i*SD_];
        const float w1 = W[(size_t)(i+1)*SD_];
        const float w2 = W[(size_t)(i+2)*SD_];
        const float w3 = W[(size_t)(i+3)*SD_];
#pragma unroll
        for (int k = 0; k < 16; ++k) {
            f32x4 q4 = *(const f32x4*)&qL[k][i];
            acc[k] += q4[0]*w0 + q4[1]*w1 + q4[2]*w2 + q4[3]*w3;
        }
    }
#pragma unroll
    for (int k = 0; k < 16; ++k)
        Sp[((size_t)(a*8 + ks)*16 + k)*SD_ + c] = acc[k];
}

__global__ void qp_reduce(const float* __restrict__ Sp, Ptr5 bq, float* __restrict__ qp) {
    const int idx = blockIdx.x*256 + threadIdx.x;   // 163840
    const int a = idx >> 15, k = (idx >> 11) & 15, c = idx & 2047;
    float s = bq.p[a][c];
#pragma unroll
    for (int ks = 0; ks < 8; ++ks)
        s += Sp[((size_t)(a*8 + ks)*16 + k)*SD_ + c];
    qp[idx] = s;
}

// ============ fused scores + softmax -> P (f32) ============
__global__ __launch_bounds__(256)
void scores_sm(const u16* __restrict__ Kb, const float* __restrict__ qp,
               const int* __restrict__ units_a, float* __restrict__ P)
{
    __shared__ float sL[16][1024];
    __shared__ float qL[16][256];
    __shared__ float red[8];
    const int u = blockIdx.x >> 3, hh = blockIdx.x & 7;
    const int ua = units_a[u];
    const int t = threadIdx.x;
    for (int i = t; i < 16*256; i += 256)
        qL[i >> 8][i & 255] = qp[(size_t)(ua*16 + (i >> 8))*SD_ + hh*256 + (i & 255)];
    __syncthreads();
    const u16* Ku = Kb + (size_t)u*1024*SD_ + hh*256;
#pragma unroll
    for (int j = 0; j < 4; ++j) {
        const int n = t + j*256;
        const u16* kr = Ku + (size_t)n*SD_;
        float acc[16] = {};
        for (int d0 = 0; d0 < 256; d0 += 8) {
            u16x8 kv8 = *(const u16x8*)(kr + d0);
            float kf[8];
#pragma unroll
            for (int e = 0; e < 8; ++e) kf[e] = bf2f(kv8[e]);
#pragma unroll
            for (int k = 0; k < 16; ++k) {
                f32x4 q0 = *(const f32x4*)&qL[k][d0];
                f32x4 q1 = *(const f32x4*)&qL[k][d0+4];
                acc[k] += q0[0]*kf[0] + q0[1]*kf[1] + q0[2]*kf[2] + q0[3]*kf[3]
                        + q1[0]*kf[4] + q1[1]*kf[5] + q1[2]*kf[6] + q1[3]*kf[7];
            }
        }
#pragma unroll
        for (int k = 0; k < 16; ++k) sL[k][n] = acc[k] * 0.0625f;
    }
    __syncthreads();
    const int lane = t & 63, wv = t >> 6;
    for (int k = 0; k < 16; ++k) {
        float v0 = sL[k][t], v1 = sL[k][t+256], v2 = sL[k][t+512], v3 = sL[k][t+768];
        float mx = fmaxf(fmaxf(v0,v1), fmaxf(v2,v3));
#pragma unroll
        for (int o = 1; o < 64; o <<= 1) mx = fmaxf(mx, __shfl_xor(mx, o));
        if (lane == 0) red[wv] = mx;
        __syncthreads();
        mx = fmaxf(fmaxf(red[0],red[1]), fmaxf(red[2],red[3]));
        float e0 = expf(v0-mx), e1 = expf(v1-mx), e2 = expf(v2-mx), e3 = expf(v3-mx);
        float s = e0+e1+e2+e3;
#pragma unroll
        for (int o = 1; o < 64; o <<= 1) s += __shfl_xor(s, o);
        if (lane == 0) red[4+wv] = s;
        __syncthreads();
        s = red[4]+red[5]+red[6]+red[7];
        const float inv = 1.0f/s;
        float* Pr = P + ((size_t)(u*8+hh)*16 + k)*1024;
        Pr[t]=e0*inv; Pr[t+256]=e1*inv; Pr[t+512]=e2*inv; Pr[t+768]=e3*inv;
        __syncthreads();
    }
}

// ============ ctx: P @ V -> ctxb (bf16) ============
__global__ __launch_bounds__(256)
void ctx_u(const u16* __restrict__ Vb, const float* __restrict__ P,
           u16* __restrict__ ctxb)
{
    __shared__ float pL[16][1024];
    const int u = blockIdx.x >> 3, hh = blockIdx.x & 7;
    const int t = threadIdx.x;
    const float* Pu = P + (size_t)(u*8+hh)*16*1024;
    for (int i = t; i < 16*1024/4; i += 256)
        ((f32x4*)&pL[0][0])[i] = ((const f32x4*)Pu)[i];
    __syncthreads();
    const u16* Vu = Vb + (size_t)u*1024*SD_ + hh*256 + t;
    float acc[16] = {};
    for (int n = 0; n < 1024; n += 4) {
        float vv0 = bf2f(Vu[(size_t)n*SD_]);
        float vv1 = bf2f(Vu[(size_t)(n+1)*SD_]);
        float vv2 = bf2f(Vu[(size_t)(n+2)*SD_]);
        float vv3 = bf2f(Vu[(size_t)(n+3)*SD_]);
#pragma unroll
        for (int k = 0; k < 16; ++k) {
            f32x4 p4 = *(const f32x4*)&pL[k][n];
            acc[k] += p4[0]*vv0 + p4[1]*vv1 + p4[2]*vv2 + p4[3]*vv3;
        }
    }
#pragma unroll
    for (int k = 0; k < 16; ++k)
        ctxb[(size_t)u*16*SD_ + k*SD_ + hh*256 + t] = f2bf(acc[k]);
}

// ============ ow-GEMM: split-K x4 ============
__global__ __launch_bounds__(256)
void gemm_ow_part(const u16* __restrict__ ctxb, const u16* __restrict__ Bslab,
                  const int* __restrict__ units_a, float* __restrict__ ctx2p)
{
    const int u = blockIdx.y, ua = units_a[u], ks = blockIdx.z;
    const int wave = threadIdx.x >> 6, lane = threadIdx.x & 63;
    const int col0 = blockIdx.x*256 + wave*64;
    const u16* A  = ctxb + (size_t)u*16*SD_;
    const u16* Bt = Bslab + (size_t)ua*SD_*SD_;
    const int fr = lane & 15, fk8 = (lane >> 4) << 3;
    f32x4 acc[4] = {};
    const int kbase = ks*512;
    for (int k0 = kbase; k0 < kbase + 512; k0 += 32) {
        bf16x8 af = *(const bf16x8*)(A + (size_t)fr*SD_ + k0 + fk8);
#pragma unroll
        for (int n = 0; n < 4; ++n) {
            bf16x8 bf8 = *(const bf16x8*)(Bt + (size_t)(col0 + n*16 + fr)*SD_ + k0 + fk8);
            acc[n] = __builtin_amdgcn_mfma_f32_16x16x32_bf16(af, bf8, acc[n], 0, 0, 0);
        }
    }
    const int fq = lane >> 4;
#pragma unroll
    for (int n = 0; n < 4; ++n)
#pragma unroll
        for (int j = 0; j < 4; ++j) {
            const int row = fq*4 + j, col = col0 + n*16 + fr;
            ctx2p[(((size_t)ks*24 + u)*16 + row)*SD_ + col] = acc[n][j];
        }
}

__global__ void gemm_ow_reduce(const float* __restrict__ ctx2p,
                               const float* __restrict__ biasSlab,
                               const int* __restrict__ units_a,
                               float* __restrict__ ctx2) {
    const int idx = blockIdx.x*256 + threadIdx.x;   // 786432
    const int u = idx / (16*SD_);
    const int rem = idx % (16*SD_);
    const int col = rem % SD_;
    float s = biasSlab[units_a[u]*SD_ + col];
#pragma unroll
    for (int ks = 0; ks < 4; ++ks)
        s += ctx2p[((size_t)ks*24*16*SD_) + (size_t)u*16*SD_ + rem];
    ctx2[idx] = s;
}

// ============ final LN ============
__global__ __launch_bounds__(256)
void ln_post_u(const float* __restrict__ ctx2, const float* __restrict__ qslab,
               const float* __restrict__ pgs, const float* __restrict__ pbs,
               const int* __restrict__ units_a, const int* __restrict__ units_b,
               float* __restrict__ out, float* __restrict__ cspec)
{
    const int k = blockIdx.x, u = blockIdx.y, tid = threadIdx.x;
    const int ua = units_a[u];
    const float* ip = ctx2 + ((size_t)u*16 + k)*SD_;
    const float* qr = qslab + ((size_t)ua*16 + k)*SD_;
    const float* g  = pgs + (size_t)ua*SD_;
    const float* bt = pbs + (size_t)ua*SD_;
    float f[8]; float s = 0.f, s2 = 0.f;
#pragma unroll
    for (int j = 0; j < 8; ++j) {
        const int c = tid + j*256;
        f[j] = ip[c] + qr[c];
        s += f[j]; s2 += f[j]*f[j];
    }
    __shared__ float sa[4], sb[4];
#pragma unroll
    for (int o = 32; o > 0; o >>= 1) { s += __shfl_down(s, o); s2 += __shfl_down(s2, o); }
    if ((tid & 63) == 0) { sa[tid >> 6] = s; sb[tid >> 6] = s2; }
    __syncthreads();
    s = sa[0]+sa[1]+sa[2]+sa[3]; s2 = sb[0]+sb[1]+sb[2]+sb[3];
    const float mean = s * (1.0f/SD_);
    const float inv  = rsqrtf(s2 * (1.0f/SD_) - mean*mean + 1e-5f);
    float* op = (u < 8) ? out + ((size_t)units_b[u]*32 + k)*SD_
                        : cspec + ((size_t)(u-8)*16 + k)*SD_;
#pragma unroll
    for (int j = 0; j < 8; ++j) { const int c = tid + j*256; op[c] = (f[j]-mean)*inv*g[c] + bt[c]; }
}

// ============ router tail ============
__global__ __launch_bounds__(256)
void rmlp_part(const float* __restrict__ pooled, const float* __restrict__ w1,
               float* __restrict__ rp) {
    const int c = blockIdx.x*256 + threadIdx.x;
    const int b = blockIdx.y, is = blockIdx.z;
    const float* pr = pooled + b*TD_ + is*512;
    const float* W = w1 + (size_t)(is*512)*512 + c;
    float s = 0.f;
    for (int i = 0; i < 512; ++i) s += pr[i] * W[(size_t)i*512];
    rp[(b*10 + is)*512 + c] = s;
}
__global__ void rmlp_reduce(const float* __restrict__ rp, const float* __restrict__ b1,
                            float* __restrict__ hid) {
    const int idx = blockIdx.x*256 + threadIdx.x;
    const int b = idx >> 9, c = idx & 511;
    float s = b1[c];
#pragma unroll
    for (int is = 0; is < 10; ++is) s += rp[(b*10 + is)*512 + c];
    hid[idx] = gelu_exact(s);
}

__global__ void router_final(const float* __restrict__ hid, const float* __restrict__ w2,
                             const float* __restrict__ b2, float* __restrict__ probs,
                             int* __restrict__ widx, float* __restrict__ wval,
                             int* __restrict__ units_a, int* __restrict__ units_b) {
    __shared__ float lg[8][4];
    __shared__ int sw[16];
    const int tid = threadIdx.x;
    if (tid < 32) {
        const int b = tid >> 2, m = tid & 3;
        float s = b2[m];
        const float* hr = hid + b*512;
        for (int i = 0; i < 512; ++i) s += hr[i]*w2[i*4 + m];
        lg[b][m] = s;
    }
    __syncthreads();
    if (tid < 8) {
        const int b = tid;
        const float l0=lg[b][0], l1=lg[b][1], l2=lg[b][2], l3=lg[b][3];
        const float mx = fmaxf(fmaxf(l0,l1),fmaxf(l2,l3));
        const float e0=expf(l0-mx), e1=expf(l1-mx), e2=expf(l2-mx), e3=expf(l3-mx);
        const float s = e0+e1+e2+e3;
        float p[4] = {e0/s, e1/s, e2/s, e3/s};
        probs[b*4+0]=p[0]; probs[b*4+1]=p[1]; probs[b*4+2]=p[2]; probs[b*4+3]=p[3];
        int i0 = 0;
        for (int m = 1; m < 4; ++m) if (p[m] > p[i0]) i0 = m;
        int i1 = -1;
        for (int m = 0; m < 4; ++m) if (m != i0 && (i1 < 0 || p[m] > p[i1])) i1 = m;
        const float w0 = p[i0], w1 = p[i1], ws = w0 + w1 + 1e-8f;
        widx[b*2]=i0; widx[b*2+1]=i1;
        wval[b*2]=w0/ws; wval[b*2+1]=w1/ws;
        sw[b*2]=i0; sw[b*2+1]=i1;
    }
    __syncthreads();
    if (tid < 24) {
        units_a[tid] = (tid < 8) ? 0 : sw[tid-8] + 1;
        units_b[tid] = (tid < 8) ? tid : ((tid-8) >> 1);
    }
}

__global__ void combine_k(const float* __restrict__ cspec, const int* __restrict__ widx,
                          const float* __restrict__ wval, float* __restrict__ out) {
    const int i = blockIdx.x*256 + threadIdx.x;
    const int c4 = i & 511;
    const int k  = (i >> 9) & 15;
    const int b  = i >> 13;
    const float w0 = wval[b*2], w1 = wval[b*2+1];
    const f32x4 v0 = ((const f32x4*)cspec)[(size_t)((2*b)  *16 + k)*512 + c4];
    const f32x4 v1 = ((const f32x4*)cspec)[(size_t)((2*b+1)*16 + k)*512 + c4];
    ((f32x4*)out)[(size_t)(b*32 + 16 + k)*512 + c4] = v0*w0 + v1*w1;
}

// ============ fused pack: bias_dw | qslab | slab8 ============
__global__ void pack_all(Ptr5 db5, Ptr5 q5, Ptr40 s8, float* __restrict__ bias_dw,
                         float* __restrict__ qslab, float* __restrict__ slab8) {
    int i = blockIdx.x*256 + threadIdx.x;   // 250880 total
    if (i < 5120) {
        bias_dw[i] = db5.p[i >> 10][i & 1023];
    } else if (i < 5120 + 163840) {
        int j = i - 5120;
        qslab[j] = q5.p[j / 32768][j % 32768];
    } else if (i < 5120 + 163840 + 81920) {
        int j = i - 5120 - 163840;
        int slab = j / 10240, rem = j % 10240;
        slab8[j] = s8.p[slab][rem / 2048][rem % 2048];
    }
}

// ============ host ============
extern "C" void kernel_launch(void* const* d_in, const int* in_sizes, int n_in,
                              void* d_out, int out_size, void* d_ws, size_t ws_size,
                              hipStream_t stream) {
    if (ws_size < 300300000ULL) return;

    const float* h = (const float*)d_in[0];
    const float* G[17]; const float* Sx[17];
    for (int i = 0; i < 17; ++i) { G[i] = (const float*)d_in[1+i]; Sx[i] = (const float*)d_in[18+i]; }
    const float* r_w1 = (const float*)d_in[35];
    const float* r_b1 = (const float*)d_in[36];
    const float* r_w2 = (const float*)d_in[37];
    const float* r_b2 = (const float*)d_in[38];

    static const size_t str[17] = {
        (size_t)TD_*BD_, BD_, (size_t)BD_*SD_, SD_, SD_, SD_, (size_t)K_*SD_,
        (size_t)SD_*SD_, (size_t)SD_*SD_, (size_t)SD_*SD_, (size_t)SD_*SD_,
        SD_, SD_, SD_, SD_, SD_, SD_ };
    auto P = [&](int pi, int a) -> const float* {
        return (a == 0) ? G[pi] : Sx[pi] + (size_t)(a-1)*str[pi];
    };

    char* w = (char*)d_ws;
    const size_t R0 = 0, R1 = 100663296, R2 = 201326592, R3 = 251658240, TAIL = 293601280;
    u16*   h_bf  = (u16*)(w + R0);
    u16*   X     = (u16*)(w + R0);
    u16*   wt_dw = (u16*)(w + R1);
    u16*   Kbuf  = (u16*)(w + R1);
    u16*   X1    = (u16*)(w + R2);
    u16*   wt_v  = (u16*)(w + R2);
    u16*   wt_ow = (u16*)(w + R2);
    u16*   wt_uw = (u16*)(w + R3);
    u16*   wt_k  = (u16*)(w + R3);
    u16*   ctxb  = (u16*)(w + R3);
    float* ctx2  = (float*)(w + R3 + 1572864);
    float* cspec = (float*)(w + R3 + 4718592);
    float* Pbuf  = (float*)(w + R3 + 6815744);
    float* ctx2p = (float*)(w + R3 + 19398656);
    float* qpp   = (float*)(w + R2);
    float* poolp = (float*)(w + R2 + 12582912);
    float* routp = (float*)(w + R2 + 33554432);
    float* qp_all  = (float*)(w + TAIL);
    float* qslab   = (float*)(w + TAIL + 655360);
    float* bias_dw = (float*)(w + TAIL + 1310720);
    float* slab8   = (float*)(w + TAIL + 1331200);
    float* pooled  = (float*)(w + TAIL + 1658880);
    float* hid     = (float*)(w + TAIL + 1822720);
    int*   widx    = (int*)  (w + TAIL + 1839104);
    float* wval    = (float*)(w + TAIL + 1839168);
    int*   units_a = (int*)  (w + TAIL + 1839232);
    int*   units_b = (int*)  (w + TAIL + 1839328);

    float* bias_uw = slab8;
    float* bias_k  = slab8 + 1*5*SD_;
    float* bias_v  = slab8 + 2*5*SD_;
    float* bias_ow = slab8 + 3*5*SD_;
    float* lng     = slab8 + 4*5*SD_;
    float* lnb     = slab8 + 5*5*SD_;
    float* pgs     = slab8 + 6*5*SD_;
    float* pbs     = slab8 + 7*5*SD_;

    float* out = (float*)d_out;

    // ---- fused conversion + pooling, then router ----
    cvt_pool<<<dim3(8, 128), 256, 0, stream>>>(h, h_bf, poolp);
    pool_reduce<<<160, 256, 0, stream>>>(poolp, pooled);
    rmlp_part<<<dim3(2, 8, 10), 256, 0, stream>>>(pooled, r_w1, routp);
    rmlp_reduce<<<16, 256, 0, stream>>>(routp, r_b1, hid);
    router_final<<<1, 64, 0, stream>>>(hid, r_w2, r_b2, out + 524288, widx, wval, units_a, units_b);

    // ---- q projections (split-K) + fused packs ----
    Ptr5 q5, wq5, bq5, db5;
    for (int a = 0; a < 5; ++a) { q5.p[a]=P(6,a); wq5.p[a]=P(7,a); bq5.p[a]=P(11,a); db5.p[a]=P(1,a); }
    qp_part<<<dim3(8, 5, 8), 256, 0, stream>>>(q5, wq5, qpp);
    qp_reduce<<<640, 256, 0, stream>>>(qpp, bq5, qp_all);
    Ptr40 s8;
    static const int slab_pi[8] = {3, 12, 13, 14, 4, 5, 15, 16};
    for (int si = 0; si < 8; ++si)
        for (int a = 0; a < 5; ++a) s8.p[si][a] = P(slab_pi[si], a);
    pack_all<<<981, 256, 0, stream>>>(db5, q5, s8, bias_dw, qslab, slab8);

    // ---- upfront transposes (batched over adapters) ----
    Ptr5 dw5, uw5, k5, v5, ow5;
    for (int a = 0; a < 5; ++a) {
        dw5.p[a] = P(0,a); uw5.p[a] = P(2,a);
        k5.p[a] = P(8,a); v5.p[a] = P(9,a); ow5.p[a] = P(10,a);
    }
    cvt_transpose5<<<dim3(TD_/64, BD_/64, 5), 256, 0, stream>>>(dw5, wt_dw, (long)BD_*TD_, TD_, BD_);
    cvt_transpose5<<<dim3(BD_/64, SD_/64, 5), 256, 0, stream>>>(uw5, wt_uw, (long)SD_*BD_, BD_, SD_);

    // ---- down-proj (gelu): gemm128 @4 blocks/CU ----
    gemm128<1, 0><<<dim3(8, 8, 24), 256, 0, stream>>>(
        h_bf, wt_dw, (long)BD_*TD_, bias_dw, BD_, X1, BD_, (long)1024*BD_, TD_, units_a, units_b);

    // ---- up-proj: gemm256 (r12 config) ----
    gemm256<0, 1><<<dim3(4, 8, 24), 512, 0, stream>>>(
        X1, wt_uw, (long)SD_*BD_, bias_uw, SD_, X, SD_, (long)1024*SD_, BD_, units_a, units_b);

    // ---- LN in place ----
    ln_rows_u<<<24*1024, 256, 0, stream>>>(X, lng, lnb, units_a);

    // ---- transposes for K/V (batched) ----
    cvt_transpose5<<<dim3(SD_/64, SD_/64, 5), 256, 0, stream>>>(k5, wt_k, (long)SD_*SD_, SD_, SD_);
    cvt_transpose5<<<dim3(SD_/64, SD_/64, 5), 256, 0, stream>>>(v5, wt_v, (long)SD_*SD_, SD_, SD_);

    // ---- K projection: gemm256 ----
    gemm256<0, 1><<<dim3(4, 8, 24), 512, 0, stream>>>(
        X, wt_k, (long)SD_*SD_, bias_k, SD_, Kbuf, SD_, (long)1024*SD_, SD_, units_a, units_b);

    // ---- scores + softmax ----
    scores_sm<<<24*8, 256, 0, stream>>>(Kbuf, qp_all, units_a, Pbuf);

    // ---- V projection ----
    gemm256<0, 1><<<dim3(4, 8, 24), 512, 0, stream>>>(
        X, wt_v, (long)SD_*SD_, bias_v, SD_, Kbuf, SD_, (long)1024*SD_, SD_, units_a, units_b);

    // ---- ow transpose (batched) ----
    cvt_transpose5<<<dim3(SD_/64, SD_/64, 5), 256, 0, stream>>>(ow5, wt_ow, (long)SD_*SD_, SD_, SD_);

    // ---- ctx = P @ V ----
    ctx_u<<<24*8, 256, 0, stream>>>(Kbuf, Pbuf, ctxb);

    // ---- output projection: split-K x4 + reduce ----
    gemm_ow_part<<<dim3(8, 24, 4), 256, 0, stream>>>(ctxb, wt_ow, units_a, ctx2p);
    gemm_ow_reduce<<<3072, 256, 0, stream>>>(ctx2p, bias_ow, units_a, ctx2);

    // ---- final LN + combine ----
    ln_post_u<<<dim3(16, 24), 256, 0, stream>>>(ctx2, qslab, pgs, pbs, units_a, units_b, out, cspec);
    combine_k<<<256, 256, 0, stream>>>(cspec, widx, wval, out);
}